// Round 2
// baseline (1619.036 us; speedup 1.0000x reference)
//
#include <hip/hip_runtime.h>

typedef unsigned short u16;
typedef unsigned int u32;

// ---------- helpers ----------
__device__ __forceinline__ float US2F(u16 u) {
    return __uint_as_float(((u32)u) << 16);
}
__device__ __forceinline__ u16 F2US(float f) {   // round-to-nearest-even bf16
    u32 u = __float_as_uint(f);
    u32 rounding = 0x7fffu + ((u >> 16) & 1u);
    u += rounding;
    return (u16)(u >> 16);
}

__device__ __forceinline__ int win_pos(int i) { return (i == 18) ? 240 : 14 * i; }
// overlap-average factor: 0.5 on strips covered by two windows, else 1
__device__ __forceinline__ float dfac(int y) {
    return ((y >= 14 && y < 240 && (y % 14) < 2) || (y >= 240 && y < 254)) ? 0.5f : 1.0f;
}
__device__ __forceinline__ float gelu_exact(float x) {
    return 0.5f * x * (1.0f + erff(x * 0.7071067811865475f));
}

// ---------- K0: zero acc ----------
__global__ void kzero(float* __restrict__ p, int n4) {
    int i = blockIdx.x * blockDim.x + threadIdx.x;
    if (i < n4) ((float4*)p)[i] = make_float4(0.f, 0.f, 0.f, 0.f);
}

// ---------- K1: window gather + LN1 + QKV ----------
// grid 722, block 256 (thread = token)
__global__ __launch_bounds__(256) void k_ln_qkv(
    const float* __restrict__ x, const float* __restrict__ n1w, const float* __restrict__ n1b,
    const float* __restrict__ wq, const float* __restrict__ wk, const float* __restrict__ wv,
    u16* __restrict__ qkv)
{
    __shared__ u16 ys[256 * 98];   // padded stride 98 -> conflict-free
    int wi = blockIdx.x;
    int b = wi / 361, r = wi % 361;
    int top = win_pos(r / 19), lf = win_pos(r % 19);
    int t = threadIdx.x;
    int gy = top + (t >> 4), gx = lf + (t & 15);
    const float* xp = x + (long)b * 96 * 65536 + (long)gy * 256 + gx;

    float s = 0.f, ss = 0.f;
    for (int c = 0; c < 96; ++c) {
        float v = xp[(long)c * 65536];
        ys[t * 98 + c] = F2US(v);
        s += v; ss += v * v;
    }
    float mu = s * (1.f / 96.f);
    float var = ss * (1.f / 96.f) - mu * mu;
    float rstd = rsqrtf(var + 1e-5f);
    for (int c = 0; c < 96; ++c) {
        float v = US2F(ys[t * 98 + c]);
        float y = (v - mu) * rstd * n1w[c] + n1b[c];
        ys[t * 98 + c] = F2US(y);
    }
    __syncthreads();

    long obase = ((long)wi * 256 + t) * 224;

    // Q (dims 0..63) and K (64..127)
    for (int m0 = 0; m0 < 64; m0 += 4) {
        float aq[4] = {0.f,0.f,0.f,0.f};
        float ak[4] = {0.f,0.f,0.f,0.f};
        for (int c = 0; c < 96; ++c) {
            float yv = US2F(ys[t * 98 + c]);
            float4 qw = *(const float4*)(wq + c * 64 + m0);
            float4 kw = *(const float4*)(wk + c * 64 + m0);
            aq[0] += yv * qw.x; aq[1] += yv * qw.y; aq[2] += yv * qw.z; aq[3] += yv * qw.w;
            ak[0] += yv * kw.x; ak[1] += yv * kw.y; ak[2] += yv * kw.z; ak[3] += yv * kw.w;
        }
        #pragma unroll
        for (int j = 0; j < 4; ++j) {
            qkv[obase + m0 + j]      = F2US(aq[j]);
            qkv[obase + 64 + m0 + j] = F2US(ak[j]);
        }
    }
    // V (dims 128..223)
    for (int m0 = 0; m0 < 96; m0 += 4) {
        float av[4] = {0.f,0.f,0.f,0.f};
        for (int c = 0; c < 96; ++c) {
            float yv = US2F(ys[t * 98 + c]);
            float4 vw = *(const float4*)(wv + c * 96 + m0);
            av[0] += yv * vw.x; av[1] += yv * vw.y; av[2] += yv * vw.z; av[3] += yv * vw.w;
        }
        #pragma unroll
        for (int j = 0; j < 4; ++j) qkv[obase + 128 + m0 + j] = F2US(av[j]);
    }
}

// ---------- K2: attention per (window, head) ----------
// grid 722*4, block 256 (thread = query token), online softmax
__global__ __launch_bounds__(256) void k_attn(const u16* __restrict__ qkv, u16* __restrict__ attn)
{
    __shared__ float ks[256 * 16];
    __shared__ float vs[256 * 24];
    int blk = blockIdx.x;
    int wi = blk >> 2, hd = blk & 3;
    int tid = threadIdx.x;
    const u16* base = qkv + (long)wi * 256 * 224;

    for (int idx = tid; idx < 256 * 16; idx += 256) {
        int j = idx >> 4, d = idx & 15;
        ks[idx] = US2F(base[j * 224 + 64 + hd * 16 + d]);   // K lives at offset 64
    }
    for (int idx = tid; idx < 256 * 24; idx += 256) {
        int j = idx / 24, d = idx - j * 24;
        vs[idx] = US2F(base[j * 224 + 128 + hd * 24 + d]);
    }
    __syncthreads();

    float q[16];
    #pragma unroll
    for (int d = 0; d < 16; ++d) q[d] = US2F(base[tid * 224 + hd * 16 + d]) * 0.25f;

    float m = -1e30f, l = 0.f;
    float o[24];
    #pragma unroll
    for (int d = 0; d < 24; ++d) o[d] = 0.f;

    for (int j = 0; j < 256; ++j) {
        float s = 0.f;
        #pragma unroll
        for (int d = 0; d < 16; ++d) s += q[d] * ks[j * 16 + d];
        float mn = fmaxf(m, s);
        float corr = __expf(m - mn);
        float p = __expf(s - mn);
        l = l * corr + p;
        #pragma unroll
        for (int d = 0; d < 24; ++d) o[d] = o[d] * corr + p * vs[j * 24 + d];
        m = mn;
    }
    float inv = 1.f / l;
    u16* op = attn + ((long)wi * 256 + tid) * 96 + hd * 24;
    #pragma unroll
    for (int d = 0; d < 24; ++d) op[d] = F2US(o[d] * inv);
}

// ---------- K3: proj + residual + scatter-add ----------
// grid 722, block 256 (thread = token)
__global__ __launch_bounds__(256) void k_proj(
    const u16* __restrict__ attn, const float* __restrict__ wproj,
    const float* __restrict__ x, float* __restrict__ accb)
{
    __shared__ u16 as[256 * 98];
    int wi = blockIdx.x;
    int b = wi / 361, r = wi % 361;
    int top = win_pos(r / 19), lf = win_pos(r % 19);
    int t = threadIdx.x;
    const u16* ap = attn + ((long)wi * 256 + t) * 96;
    for (int k = 0; k < 96; ++k) as[t * 98 + k] = ap[k];
    __syncthreads();

    int gy = top + (t >> 4), gx = lf + (t & 15);
    long pix = (long)gy * 256 + gx;

    for (int c0 = 0; c0 < 96; c0 += 4) {
        float a4[4] = {0.f,0.f,0.f,0.f};
        for (int k = 0; k < 96; ++k) {
            float av = US2F(as[t * 98 + k]);
            float4 w = *(const float4*)(wproj + k * 96 + c0);
            a4[0] += av * w.x; a4[1] += av * w.y; a4[2] += av * w.z; a4[3] += av * w.w;
        }
        #pragma unroll
        for (int j = 0; j < 4; ++j) {
            int c = c0 + j;
            long gi = (long)(b * 96 + c) * 65536 + pix;
            float val = a4[j] + x[gi];
            atomicAdd(accb + gi, val);
        }
    }
}

// ---------- K5: LN2 + fc1 + GELU -> y1 planes (b,192,h,w) ----------
// grid 2048 (64 px/block), block 256
__global__ __launch_bounds__(256) void k_ln2_fc1(
    const float* __restrict__ accb,
    const float* __restrict__ n2w, const float* __restrict__ n2b,
    const float* __restrict__ fc1w, const float* __restrict__ fc1b,
    u16* __restrict__ y1)
{
    __shared__ float xs[64 * 97];
    __shared__ float mu_s[64], rs_s[64];
    int p0 = blockIdx.x * 64;
    int b = p0 >> 16, pp = p0 & 65535;
    int tid = threadIdx.x;

    for (int idx = tid; idx < 64 * 96; idx += 256) {
        int c = idx >> 6, px = idx & 63;
        int p = pp + px;
        float f = dfac(p >> 8) * dfac(p & 255);
        xs[px * 97 + c] = accb[(long)(b * 96 + c) * 65536 + p] * f;
    }
    __syncthreads();
    if (tid < 64) {
        float s = 0.f, ss = 0.f;
        for (int c = 0; c < 96; ++c) { float v = xs[tid * 97 + c]; s += v; ss += v * v; }
        float mu = s * (1.f / 96.f);
        float var = ss * (1.f / 96.f) - mu * mu;
        mu_s[tid] = mu; rs_s[tid] = rsqrtf(var + 1e-5f);
    }
    __syncthreads();
    for (int idx = tid; idx < 64 * 96; idx += 256) {
        int c = idx >> 6, px = idx & 63;
        xs[px * 97 + c] = (xs[px * 97 + c] - mu_s[px]) * rs_s[px] * n2w[c] + n2b[c];
    }
    __syncthreads();

    int px = tid & 63;
    int mb = tid >> 6;     // 0..3, each covers 48 output dims
    for (int g = 0; g < 12; ++g) {
        int m0 = mb * 48 + g * 4;
        float a4[4] = {0.f,0.f,0.f,0.f};
        for (int c = 0; c < 96; ++c) {
            float xv = xs[px * 97 + c];
            float4 w = *(const float4*)(fc1w + c * 192 + m0);
            a4[0] += xv * w.x; a4[1] += xv * w.y; a4[2] += xv * w.z; a4[3] += xv * w.w;
        }
        #pragma unroll
        for (int j = 0; j < 4; ++j) {
            int m = m0 + j;
            float v = gelu_exact(a4[j] + fc1b[m]);
            y1[(long)(b * 192 + m) * 65536 + pp + px] = F2US(v);
        }
    }
}

// ---------- K6: depthwise 5x5 conv + GELU + add -> y2 ----------
// grid 512 (b x 16x16 tiles of 16x16 px), block 256
__global__ __launch_bounds__(256) void k_dwconv(
    const u16* __restrict__ y1, const float* __restrict__ dww, const float* __restrict__ dwb,
    u16* __restrict__ y2)
{
    __shared__ float tile[20 * 20];
    __shared__ float wsm[25];
    int blk = blockIdx.x;
    int b = blk >> 8; int t8 = blk & 255;
    int by = (t8 >> 4) << 4, bx = (t8 & 15) << 4;
    int tid = threadIdx.x;
    int ty = tid >> 4, tx = tid & 15;
    int gy = by + ty, gx = bx + tx;

    for (int m = 0; m < 192; ++m) {
        const u16* plane = y1 + (long)(b * 192 + m) * 65536;
        if (tid < 25) wsm[tid] = dww[m * 25 + tid];
        for (int idx = tid; idx < 400; idx += 256) {
            int ly = idx / 20, lx = idx - ly * 20;
            int sy = by + ly - 2, sx = bx + lx - 2;
            float v = 0.f;
            if (sy >= 0 && sy < 256 && sx >= 0 && sx < 256) v = US2F(plane[sy * 256 + sx]);
            tile[idx] = v;
        }
        __syncthreads();
        float acc = 0.f;
        #pragma unroll
        for (int ky = 0; ky < 5; ++ky)
            #pragma unroll
            for (int kx = 0; kx < 5; ++kx)
                acc += tile[(ty + ky) * 20 + tx + kx] * wsm[ky * 5 + kx];
        float center = tile[(ty + 2) * 20 + tx + 2];
        float v = center + gelu_exact(acc + dwb[m]);
        y2[(long)(b * 192 + m) * 65536 + gy * 256 + gx] = F2US(v);
        __syncthreads();
    }
}

// ---------- K7: fc2 + bias + residual -> out ----------
// grid 2048 (64 px/block), block 256
__global__ __launch_bounds__(256) void k_fc2(
    const u16* __restrict__ y2, const float* __restrict__ fc2w, const float* __restrict__ fc2b,
    const float* __restrict__ accb, float* __restrict__ out)
{
    __shared__ u16 ys2[64 * 194];
    int p0 = blockIdx.x * 64;
    int b = p0 >> 16, pp = p0 & 65535;
    int tid = threadIdx.x;
    for (int idx = tid; idx < 64 * 192; idx += 256) {
        int m = idx >> 6, px = idx & 63;
        ys2[px * 194 + m] = y2[(long)(b * 192 + m) * 65536 + pp + px];
    }
    __syncthreads();

    int px = tid & 63;
    int cb = tid >> 6;     // 0..3, each covers 24 output channels
    int p = pp + px;
    float f = dfac(p >> 8) * dfac(p & 255);
    for (int g = 0; g < 6; ++g) {
        int c0 = cb * 24 + g * 4;
        float a4[4] = {0.f,0.f,0.f,0.f};
        for (int m = 0; m < 192; ++m) {
            float yv = US2F(ys2[px * 194 + m]);
            float4 w = *(const float4*)(fc2w + m * 96 + c0);
            a4[0] += yv * w.x; a4[1] += yv * w.y; a4[2] += yv * w.z; a4[3] += yv * w.w;
        }
        #pragma unroll
        for (int j = 0; j < 4; ++j) {
            int c = c0 + j;
            long gi = (long)(b * 96 + c) * 65536 + p;
            out[gi] = a4[j] + fc2b[c] + accb[gi] * f;
        }
    }
}

extern "C" void kernel_launch(void* const* d_in, const int* in_sizes, int n_in,
                              void* d_out, int out_size, void* d_ws, size_t ws_size,
                              hipStream_t stream)
{
    const float* x     = (const float*)d_in[0];
    const float* n1w   = (const float*)d_in[1];
    const float* n1b   = (const float*)d_in[2];
    const float* wq    = (const float*)d_in[3];
    const float* wk    = (const float*)d_in[4];
    const float* wv    = (const float*)d_in[5];
    const float* wproj = (const float*)d_in[6];
    const float* n2w   = (const float*)d_in[7];
    const float* n2b   = (const float*)d_in[8];
    const float* fc1w  = (const float*)d_in[9];
    const float* fc1b  = (const float*)d_in[10];
    const float* dww   = (const float*)d_in[11];
    const float* dwb   = (const float*)d_in[12];
    const float* fc2w  = (const float*)d_in[13];
    const float* fc2b  = (const float*)d_in[14];

    char* ws = (char*)d_ws;
    float* accb = (float*)ws;                       // 50,331,648 B fp32 (b,96,256,256)
    u16* qkv  = (u16*)(ws + 50331648);              // 82,804,736 B bf16 (722,256,224)
    u16* attn = (u16*)(ws + 133136384);             // 35,487,744 B bf16 (722,256,96)
    u16* y1   = (u16*)(ws + 50331648);              // reuse qkv region (dead after k_attn)
    u16* y2   = (u16*)(ws + 100663296);             // 50,331,648 B bf16 (overlaps attn; attn dead by then)
    float* out = (float*)d_out;

    kzero<<<12288, 256, 0, stream>>>(accb, 3145728);
    k_ln_qkv<<<722, 256, 0, stream>>>(x, n1w, n1b, wq, wk, wv, qkv);
    k_attn<<<2888, 256, 0, stream>>>(qkv, attn);
    k_proj<<<722, 256, 0, stream>>>(attn, wproj, x, accb);
    k_ln2_fc1<<<2048, 256, 0, stream>>>(accb, n2w, n2b, fc1w, fc1b, y1);
    k_dwconv<<<512, 256, 0, stream>>>(y1, dww, dwb, y2);
    k_fc2<<<2048, 256, 0, stream>>>(y2, fc2w, fc2b, accb, out);
}

// Round 3
// 1394.827 us; speedup vs baseline: 1.1607x; 1.1607x over previous
//
#include <hip/hip_runtime.h>

typedef unsigned short u16;
typedef unsigned int u32;
typedef __attribute__((ext_vector_type(8))) short bf16x8;
typedef __attribute__((ext_vector_type(4))) float f32x4;

// ---------- helpers ----------
__device__ __forceinline__ float US2F(u16 u) {
    return __uint_as_float(((u32)u) << 16);
}
__device__ __forceinline__ u16 F2US(float f) {   // round-to-nearest-even bf16
    u32 u = __float_as_uint(f);
    u32 rounding = 0x7fffu + ((u >> 16) & 1u);
    u += rounding;
    return (u16)(u >> 16);
}

__device__ __forceinline__ int win_pos(int i) { return (i == 18) ? 240 : 14 * i; }
// overlap-average factor: 0.5 on strips covered by two windows, else 1
__device__ __forceinline__ float dfac(int y) {
    return ((y >= 14 && y < 240 && (y % 14) < 2) || (y >= 240 && y < 254)) ? 0.5f : 1.0f;
}
__device__ __forceinline__ float gelu_exact(float x) {
    return 0.5f * x * (1.0f + erff(x * 0.7071067811865475f));
}

// ---------- K0: zero acc ----------
__global__ void kzero(float* __restrict__ p, int n4) {
    int i = blockIdx.x * blockDim.x + threadIdx.x;
    if (i < n4) ((float4*)p)[i] = make_float4(0.f, 0.f, 0.f, 0.f);
}

// ---------- K1: window gather + LN1 + QKV ----------
// grid 722, block 256 (thread = token)
__global__ __launch_bounds__(256) void k_ln_qkv(
    const float* __restrict__ x, const float* __restrict__ n1w, const float* __restrict__ n1b,
    const float* __restrict__ wq, const float* __restrict__ wk, const float* __restrict__ wv,
    u16* __restrict__ qkv)
{
    __shared__ u16 ys[256 * 98];   // padded stride 98 -> conflict-free
    int wi = blockIdx.x;
    int b = wi / 361, r = wi % 361;
    int top = win_pos(r / 19), lf = win_pos(r % 19);
    int t = threadIdx.x;
    int gy = top + (t >> 4), gx = lf + (t & 15);
    const float* xp = x + (long)b * 96 * 65536 + (long)gy * 256 + gx;

    float s = 0.f, ss = 0.f;
    for (int c = 0; c < 96; ++c) {
        float v = xp[(long)c * 65536];
        ys[t * 98 + c] = F2US(v);
        s += v; ss += v * v;
    }
    float mu = s * (1.f / 96.f);
    float var = ss * (1.f / 96.f) - mu * mu;
    float rstd = rsqrtf(var + 1e-5f);
    for (int c = 0; c < 96; ++c) {
        float v = US2F(ys[t * 98 + c]);
        float y = (v - mu) * rstd * n1w[c] + n1b[c];
        ys[t * 98 + c] = F2US(y);
    }
    __syncthreads();

    long obase = ((long)wi * 256 + t) * 224;

    // Q (dims 0..63) and K (64..127)
    for (int m0 = 0; m0 < 64; m0 += 4) {
        float aq[4] = {0.f,0.f,0.f,0.f};
        float ak[4] = {0.f,0.f,0.f,0.f};
        for (int c = 0; c < 96; ++c) {
            float yv = US2F(ys[t * 98 + c]);
            float4 qw = *(const float4*)(wq + c * 64 + m0);
            float4 kw = *(const float4*)(wk + c * 64 + m0);
            aq[0] += yv * qw.x; aq[1] += yv * qw.y; aq[2] += yv * qw.z; aq[3] += yv * qw.w;
            ak[0] += yv * kw.x; ak[1] += yv * kw.y; ak[2] += yv * kw.z; ak[3] += yv * kw.w;
        }
        #pragma unroll
        for (int j = 0; j < 4; ++j) {
            qkv[obase + m0 + j]      = F2US(aq[j]);
            qkv[obase + 64 + m0 + j] = F2US(ak[j]);
        }
    }
    // V (dims 128..223)
    for (int m0 = 0; m0 < 96; m0 += 4) {
        float av[4] = {0.f,0.f,0.f,0.f};
        for (int c = 0; c < 96; ++c) {
            float yv = US2F(ys[t * 98 + c]);
            float4 vw = *(const float4*)(wv + c * 96 + m0);
            av[0] += yv * vw.x; av[1] += yv * vw.y; av[2] += yv * vw.z; av[3] += yv * vw.w;
        }
        #pragma unroll
        for (int j = 0; j < 4; ++j) qkv[obase + 128 + m0 + j] = F2US(av[j]);
    }
}

// ---------- K2: MFMA flash attention ----------
// grid 722*2 (window x head-pair), block 128 (2 waves, wave = one head)
// qkv layout per token: [0..63]=Q, [64..127]=K, [128..223]=V (bf16)
#define PSTR 264   // LDS row stride in bf16 units (16B-aligned, conflict-light)
__global__ __launch_bounds__(128) void k_attn_mfma(const u16* __restrict__ qkv, u16* __restrict__ attn)
{
    __shared__ __align__(16) u16 vt[2][24 * PSTR];   // V^T per wave: [vdim][key]
    __shared__ __align__(16) u16 pls[2][16 * PSTR];  // P per wave: [qrow][key]

    int wi = blockIdx.x >> 1;
    int pairid = blockIdx.x & 1;
    int wv = threadIdx.x >> 6;         // wave id 0/1
    int hd = pairid * 2 + wv;          // head 0..3
    int lane = threadIdx.x & 63;
    int l15 = lane & 15;
    int kg = lane >> 4;                // k-group 0..3

    const u16* base = qkv + (long)wi * 256 * 224;
    u16* vtp = vt[wv];
    u16* plp = pls[wv];

    const bf16x8 zf = {0,0,0,0,0,0,0,0};
    const f32x4 zc = {0.f,0.f,0.f,0.f};

    // ---- stage V^T into LDS (wave-private) ----
    for (int rd = 0; rd < 4; ++rd) {
        int tok = rd * 64 + lane;
        const u16* vp = base + tok * 224 + 128 + hd * 24;
        bf16x8 v0 = *(const bf16x8*)(vp);
        bf16x8 v1 = *(const bf16x8*)(vp + 8);
        bf16x8 v2 = *(const bf16x8*)(vp + 16);
        #pragma unroll
        for (int j = 0; j < 8; ++j) {
            vtp[(j)      * PSTR + tok] = (u16)v0[j];
            vtp[(j + 8)  * PSTR + tok] = (u16)v1[j];
            vtp[(j + 16) * PSTR + tok] = (u16)v2[j];
        }
    }

    // ---- cache all K B-fragments in registers (reused by all 16 q-tiles) ----
    bf16x8 kfr[16];
    #pragma unroll
    for (int nt = 0; nt < 16; ++nt) {
        int key = nt * 16 + l15;
        kfr[nt] = (kg < 2) ? *(const bf16x8*)(base + key * 224 + 64 + hd * 16 + kg * 8) : zf;
    }
    __syncthreads();   // V^T staged (also orders LDS writes before reads)

    for (int qt = 0; qt < 16; ++qt) {
        // Q A-fragment: A[m=l15][k=kg*8+j], head_dim 16 padded to 32 with zeros
        int qtok = qt * 16 + l15;
        bf16x8 qfr = (kg < 2) ? *(const bf16x8*)(base + qtok * 224 + hd * 16 + kg * 8) : zf;

        // S row-block: 16 col-tiles
        f32x4 S[16];
        #pragma unroll
        for (int nt = 0; nt < 16; ++nt)
            S[nt] = __builtin_amdgcn_mfma_f32_16x16x32_bf16(qfr, kfr[nt], zc, 0, 0, 0);

        // scale by 1/sqrt(16)
        #pragma unroll
        for (int nt = 0; nt < 16; ++nt) S[nt] *= 0.25f;

        // row max (rows live in 16-lane groups; reg r = row (lane>>4)*4+r)
        float mx[4];
        #pragma unroll
        for (int r = 0; r < 4; ++r) {
            float m = S[0][r];
            #pragma unroll
            for (int nt = 1; nt < 16; ++nt) m = fmaxf(m, S[nt][r]);
            #pragma unroll
            for (int msk = 1; msk < 16; msk <<= 1) m = fmaxf(m, __shfl_xor(m, msk));
            mx[r] = m;
        }
        // exp
        #pragma unroll
        for (int nt = 0; nt < 16; ++nt) {
            #pragma unroll
            for (int r = 0; r < 4; ++r) S[nt][r] = __expf(S[nt][r] - mx[r]);
        }
        // row sum
        float li[4];
        #pragma unroll
        for (int r = 0; r < 4; ++r) {
            float s = S[0][r];
            #pragma unroll
            for (int nt = 1; nt < 16; ++nt) s += S[nt][r];
            #pragma unroll
            for (int msk = 1; msk < 16; msk <<= 1) s += __shfl_xor(s, msk);
            li[r] = 1.f / s;
        }
        // write P to LDS (row-major [qrow][key], bf16)
        #pragma unroll
        for (int nt = 0; nt < 16; ++nt) {
            #pragma unroll
            for (int r = 0; r < 4; ++r) {
                int R = kg * 4 + r;
                plp[R * PSTR + nt * 16 + l15] = F2US(S[nt][r]);
            }
        }
        __syncthreads();   // order P writes before A-frag reads (both waves symmetric)

        // O = P x V  (2 n-tiles: vdims 0..15, 16..23 + pad)
        f32x4 O0 = zc, O1 = zc;
        int vd1 = 16 + l15;
        #pragma unroll
        for (int ks = 0; ks < 8; ++ks) {
            bf16x8 af = *(const bf16x8*)(plp + l15 * PSTR + ks * 32 + kg * 8);
            bf16x8 b0 = *(const bf16x8*)(vtp + l15 * PSTR + ks * 32 + kg * 8);
            bf16x8 b1 = (l15 < 8) ? *(const bf16x8*)(vtp + vd1 * PSTR + ks * 32 + kg * 8) : zf;
            O0 = __builtin_amdgcn_mfma_f32_16x16x32_bf16(af, b0, O0, 0, 0, 0);
            O1 = __builtin_amdgcn_mfma_f32_16x16x32_bf16(af, b1, O1, 0, 0, 0);
        }
        // normalize + store: C/D row=kg*4+r (qrow), col=l15 (vdim)
        #pragma unroll
        for (int r = 0; r < 4; ++r) {
            int R = kg * 4 + r;
            long tok = (long)wi * 256 + qt * 16 + R;
            attn[tok * 96 + hd * 24 + l15] = F2US(O0[r] * li[r]);
            if (l15 < 8) attn[tok * 96 + hd * 24 + 16 + l15] = F2US(O1[r] * li[r]);
        }
        __syncthreads();   // protect P buffer before next q-tile overwrites
    }
}

// ---------- K3: proj + residual + scatter-add ----------
// grid 722, block 256 (thread = token)
__global__ __launch_bounds__(256) void k_proj(
    const u16* __restrict__ attn, const float* __restrict__ wproj,
    const float* __restrict__ x, float* __restrict__ accb)
{
    __shared__ u16 as[256 * 98];
    int wi = blockIdx.x;
    int b = wi / 361, r = wi % 361;
    int top = win_pos(r / 19), lf = win_pos(r % 19);
    int t = threadIdx.x;
    const u16* ap = attn + ((long)wi * 256 + t) * 96;
    for (int k = 0; k < 96; ++k) as[t * 98 + k] = ap[k];
    __syncthreads();

    int gy = top + (t >> 4), gx = lf + (t & 15);
    long pix = (long)gy * 256 + gx;

    for (int c0 = 0; c0 < 96; c0 += 4) {
        float a4[4] = {0.f,0.f,0.f,0.f};
        for (int k = 0; k < 96; ++k) {
            float av = US2F(as[t * 98 + k]);
            float4 w = *(const float4*)(wproj + k * 96 + c0);
            a4[0] += av * w.x; a4[1] += av * w.y; a4[2] += av * w.z; a4[3] += av * w.w;
        }
        #pragma unroll
        for (int j = 0; j < 4; ++j) {
            int c = c0 + j;
            long gi = (long)(b * 96 + c) * 65536 + pix;
            float val = a4[j] + x[gi];
            atomicAdd(accb + gi, val);
        }
    }
}

// ---------- K5: LN2 + fc1 + GELU -> y1 planes (b,192,h,w) ----------
// grid 2048 (64 px/block), block 256
__global__ __launch_bounds__(256) void k_ln2_fc1(
    const float* __restrict__ accb,
    const float* __restrict__ n2w, const float* __restrict__ n2b,
    const float* __restrict__ fc1w, const float* __restrict__ fc1b,
    u16* __restrict__ y1)
{
    __shared__ float xs[64 * 97];
    __shared__ float mu_s[64], rs_s[64];
    int p0 = blockIdx.x * 64;
    int b = p0 >> 16, pp = p0 & 65535;
    int tid = threadIdx.x;

    for (int idx = tid; idx < 64 * 96; idx += 256) {
        int c = idx >> 6, px = idx & 63;
        int p = pp + px;
        float f = dfac(p >> 8) * dfac(p & 255);
        xs[px * 97 + c] = accb[(long)(b * 96 + c) * 65536 + p] * f;
    }
    __syncthreads();
    if (tid < 64) {
        float s = 0.f, ss = 0.f;
        for (int c = 0; c < 96; ++c) { float v = xs[tid * 97 + c]; s += v; ss += v * v; }
        float mu = s * (1.f / 96.f);
        float var = ss * (1.f / 96.f) - mu * mu;
        mu_s[tid] = mu; rs_s[tid] = rsqrtf(var + 1e-5f);
    }
    __syncthreads();
    for (int idx = tid; idx < 64 * 96; idx += 256) {
        int c = idx >> 6, px = idx & 63;
        xs[px * 97 + c] = (xs[px * 97 + c] - mu_s[px]) * rs_s[px] * n2w[c] + n2b[c];
    }
    __syncthreads();

    int px = tid & 63;
    int mb = tid >> 6;     // 0..3, each covers 48 output dims
    for (int g = 0; g < 12; ++g) {
        int m0 = mb * 48 + g * 4;
        float a4[4] = {0.f,0.f,0.f,0.f};
        for (int c = 0; c < 96; ++c) {
            float xv = xs[px * 97 + c];
            float4 w = *(const float4*)(fc1w + c * 192 + m0);
            a4[0] += xv * w.x; a4[1] += xv * w.y; a4[2] += xv * w.z; a4[3] += xv * w.w;
        }
        #pragma unroll
        for (int j = 0; j < 4; ++j) {
            int m = m0 + j;
            float v = gelu_exact(a4[j] + fc1b[m]);
            y1[(long)(b * 192 + m) * 65536 + pp + px] = F2US(v);
        }
    }
}

// ---------- K6: depthwise 5x5 conv + GELU + add -> y2 ----------
// grid 512 (b x 16x16 tiles of 16x16 px), block 256
__global__ __launch_bounds__(256) void k_dwconv(
    const u16* __restrict__ y1, const float* __restrict__ dww, const float* __restrict__ dwb,
    u16* __restrict__ y2)
{
    __shared__ float tile[20 * 20];
    __shared__ float wsm[25];
    int blk = blockIdx.x;
    int b = blk >> 8; int t8 = blk & 255;
    int by = (t8 >> 4) << 4, bx = (t8 & 15) << 4;
    int tid = threadIdx.x;
    int ty = tid >> 4, tx = tid & 15;
    int gy = by + ty, gx = bx + tx;

    for (int m = 0; m < 192; ++m) {
        const u16* plane = y1 + (long)(b * 192 + m) * 65536;
        if (tid < 25) wsm[tid] = dww[m * 25 + tid];
        for (int idx = tid; idx < 400; idx += 256) {
            int ly = idx / 20, lx = idx - ly * 20;
            int sy = by + ly - 2, sx = bx + lx - 2;
            float v = 0.f;
            if (sy >= 0 && sy < 256 && sx >= 0 && sx < 256) v = US2F(plane[sy * 256 + sx]);
            tile[idx] = v;
        }
        __syncthreads();
        float acc = 0.f;
        #pragma unroll
        for (int ky = 0; ky < 5; ++ky)
            #pragma unroll
            for (int kx = 0; kx < 5; ++kx)
                acc += tile[(ty + ky) * 20 + tx + kx] * wsm[ky * 5 + kx];
        float center = tile[(ty + 2) * 20 + tx + 2];
        float v = center + gelu_exact(acc + dwb[m]);
        y2[(long)(b * 192 + m) * 65536 + gy * 256 + gx] = F2US(v);
        __syncthreads();
    }
}

// ---------- K7: fc2 + bias + residual -> out ----------
// grid 2048 (64 px/block), block 256
__global__ __launch_bounds__(256) void k_fc2(
    const u16* __restrict__ y2, const float* __restrict__ fc2w, const float* __restrict__ fc2b,
    const float* __restrict__ accb, float* __restrict__ out)
{
    __shared__ u16 ys2[64 * 194];
    int p0 = blockIdx.x * 64;
    int b = p0 >> 16, pp = p0 & 65535;
    int tid = threadIdx.x;
    for (int idx = tid; idx < 64 * 192; idx += 256) {
        int m = idx >> 6, px = idx & 63;
        ys2[px * 194 + m] = y2[(long)(b * 192 + m) * 65536 + pp + px];
    }
    __syncthreads();

    int px = tid & 63;
    int cb = tid >> 6;     // 0..3, each covers 24 output channels
    int p = pp + px;
    float f = dfac(p >> 8) * dfac(p & 255);
    for (int g = 0; g < 6; ++g) {
        int c0 = cb * 24 + g * 4;
        float a4[4] = {0.f,0.f,0.f,0.f};
        for (int m = 0; m < 192; ++m) {
            float yv = US2F(ys2[px * 194 + m]);
            float4 w = *(const float4*)(fc2w + m * 96 + c0);
            a4[0] += yv * w.x; a4[1] += yv * w.y; a4[2] += yv * w.z; a4[3] += yv * w.w;
        }
        #pragma unroll
        for (int j = 0; j < 4; ++j) {
            int c = c0 + j;
            long gi = (long)(b * 96 + c) * 65536 + p;
            out[gi] = a4[j] + fc2b[c] + accb[gi] * f;
        }
    }
}

extern "C" void kernel_launch(void* const* d_in, const int* in_sizes, int n_in,
                              void* d_out, int out_size, void* d_ws, size_t ws_size,
                              hipStream_t stream)
{
    const float* x     = (const float*)d_in[0];
    const float* n1w   = (const float*)d_in[1];
    const float* n1b   = (const float*)d_in[2];
    const float* wq    = (const float*)d_in[3];
    const float* wk    = (const float*)d_in[4];
    const float* wv    = (const float*)d_in[5];
    const float* wproj = (const float*)d_in[6];
    const float* n2w   = (const float*)d_in[7];
    const float* n2b   = (const float*)d_in[8];
    const float* fc1w  = (const float*)d_in[9];
    const float* fc1b  = (const float*)d_in[10];
    const float* dww   = (const float*)d_in[11];
    const float* dwb   = (const float*)d_in[12];
    const float* fc2w  = (const float*)d_in[13];
    const float* fc2b  = (const float*)d_in[14];

    char* ws = (char*)d_ws;
    float* accb = (float*)ws;                       // 50,331,648 B fp32 (b,96,256,256)
    u16* qkv  = (u16*)(ws + 50331648);              // 82,804,736 B bf16 (722,256,224)
    u16* attn = (u16*)(ws + 133136384);             // 35,487,744 B bf16 (722,256,96)
    u16* y1   = (u16*)(ws + 50331648);              // reuse qkv region (dead after attention)
    u16* y2   = (u16*)(ws + 100663296);             // 50,331,648 B bf16 (overlaps attn; attn dead by then)
    float* out = (float*)d_out;

    kzero<<<12288, 256, 0, stream>>>(accb, 3145728);
    k_ln_qkv<<<722, 256, 0, stream>>>(x, n1w, n1b, wq, wk, wv, qkv);
    k_attn_mfma<<<1444, 128, 0, stream>>>(qkv, attn);
    k_proj<<<722, 256, 0, stream>>>(attn, wproj, x, accb);
    k_ln2_fc1<<<2048, 256, 0, stream>>>(accb, n2w, n2b, fc1w, fc1b, y1);
    k_dwconv<<<512, 256, 0, stream>>>(y1, dww, dwb, y2);
    k_fc2<<<2048, 256, 0, stream>>>(y2, fc2w, fc2b, accb, out);
}

// Round 4
// 1042.952 us; speedup vs baseline: 1.5524x; 1.3374x over previous
//
#include <hip/hip_runtime.h>

typedef unsigned short u16;
typedef unsigned int u32;
typedef __attribute__((ext_vector_type(8))) short bf16x8;
typedef __attribute__((ext_vector_type(4))) float f32x4;

// ---------- helpers ----------
__device__ __forceinline__ float US2F(u16 u) {
    return __uint_as_float(((u32)u) << 16);
}
__device__ __forceinline__ u16 F2US(float f) {   // round-to-nearest-even bf16
    u32 u = __float_as_uint(f);
    u32 rounding = 0x7fffu + ((u >> 16) & 1u);
    u += rounding;
    return (u16)(u >> 16);
}

__device__ __forceinline__ int win_pos(int i) { return (i == 18) ? 240 : 14 * i; }
// overlap-average factor: 0.5 on strips covered by two windows, else 1
__device__ __forceinline__ float dfac(int y) {
    return ((y >= 14 && y < 240 && (y % 14) < 2) || (y >= 240 && y < 254)) ? 0.5f : 1.0f;
}
__device__ __forceinline__ float gelu_exact(float x) {
    return 0.5f * x * (1.0f + erff(x * 0.7071067811865475f));
}

// ---------- K0: zero acc ----------
__global__ void kzero(float* __restrict__ p, int n4) {
    int i = blockIdx.x * blockDim.x + threadIdx.x;
    if (i < n4) ((float4*)p)[i] = make_float4(0.f, 0.f, 0.f, 0.f);
}

// ---------- Kprep: transpose + bf16-cast all GEMM weights ----------
// wT element layout: [0,21504) wqkvT[224][96]; [21504,30720) wprojT[96][96];
// [30720,49152) fc1T[192][96]; [49152,67584) fc2T[96][192]
__global__ __launch_bounds__(256) void k_prep(
    const float* __restrict__ wq, const float* __restrict__ wk, const float* __restrict__ wv,
    const float* __restrict__ wproj, const float* __restrict__ fc1w, const float* __restrict__ fc2w,
    u16* __restrict__ wT)
{
    int i = blockIdx.x * 256 + threadIdx.x;
    if (i < 21504) {
        int m = i / 96, c = i % 96;
        float v = (m < 64) ? wq[c * 64 + m] : ((m < 128) ? wk[c * 64 + m - 64] : wv[c * 96 + m - 128]);
        wT[i] = F2US(v);
    } else if (i < 30720) {
        int j = i - 21504; int n = j / 96, k = j % 96;
        wT[i] = F2US(wproj[k * 96 + n]);
    } else if (i < 49152) {
        int j = i - 30720; int n = j / 96, k = j % 96;
        wT[i] = F2US(fc1w[k * 192 + n]);
    } else if (i < 67584) {
        int j = i - 49152; int n = j / 192, k = j % 192;
        wT[i] = F2US(fc2w[k * 96 + n]);
    }
}

// ---------- K1: window gather + LN1 + QKV (MFMA) ----------
// grid 722, block 256 (4 waves); M=256 tokens, N=224, K=96
#define YSTR 104   // bf16 row stride: 208 B = 13*16, rows 16B-aligned, 2-way banks (free)
__global__ __launch_bounds__(256) void k_ln_qkv_mfma(
    const float* __restrict__ x, const float* __restrict__ n1w, const float* __restrict__ n1b,
    const u16* __restrict__ wqkvT, u16* __restrict__ qkv)
{
    __shared__ __align__(16) u16 ys[256 * YSTR];
    int wi = blockIdx.x;
    int b = wi / 361, r = wi % 361;
    int top = win_pos(r / 19), lf = win_pos(r % 19);
    int t = threadIdx.x;
    int gy = top + (t >> 4), gx = lf + (t & 15);
    const float* xp = x + (long)b * 96 * 65536 + (long)gy * 256 + gx;

    float s = 0.f, ss = 0.f;
    for (int c = 0; c < 96; ++c) {
        float v = xp[(long)c * 65536];
        ys[t * YSTR + c] = F2US(v);
        s += v; ss += v * v;
    }
    float mu = s * (1.f / 96.f);
    float var = ss * (1.f / 96.f) - mu * mu;
    float rstd = rsqrtf(var + 1e-5f);
    for (int c = 0; c < 96; ++c) {
        float v = US2F(ys[t * YSTR + c]);
        ys[t * YSTR + c] = F2US((v - mu) * rstd * n1w[c] + n1b[c]);
    }
    __syncthreads();

    int wvid = t >> 6, lane = t & 63, l15 = lane & 15, kg = lane >> 4;
    const f32x4 zc = {0.f, 0.f, 0.f, 0.f};

    for (int i = 0; i < 4; ++i) {
        int rt = wvid * 4 + i;
        bf16x8 a0 = *(const bf16x8*)(ys + (rt * 16 + l15) * YSTR + 0  + kg * 8);
        bf16x8 a1 = *(const bf16x8*)(ys + (rt * 16 + l15) * YSTR + 32 + kg * 8);
        bf16x8 a2 = *(const bf16x8*)(ys + (rt * 16 + l15) * YSTR + 64 + kg * 8);
        for (int nt = 0; nt < 14; ++nt) {
            const u16* wp = wqkvT + (nt * 16 + l15) * 96 + kg * 8;
            f32x4 acc = __builtin_amdgcn_mfma_f32_16x16x32_bf16(a0, *(const bf16x8*)(wp), zc, 0, 0, 0);
            acc = __builtin_amdgcn_mfma_f32_16x16x32_bf16(a1, *(const bf16x8*)(wp + 32), acc, 0, 0, 0);
            acc = __builtin_amdgcn_mfma_f32_16x16x32_bf16(a2, *(const bf16x8*)(wp + 64), acc, 0, 0, 0);
            u16* op = qkv + ((long)wi * 256 + rt * 16 + kg * 4) * 224 + nt * 16 + l15;
            #pragma unroll
            for (int rr = 0; rr < 4; ++rr) op[rr * 224] = F2US(acc[rr]);
        }
    }
}

// ---------- K2: MFMA flash attention ----------
// grid 722*2 (window x head-pair), block 128 (2 waves, wave = one head)
#define PSTR 264
__global__ __launch_bounds__(128) void k_attn_mfma(const u16* __restrict__ qkv, u16* __restrict__ attn)
{
    __shared__ __align__(16) u16 vt[2][24 * PSTR];   // V^T per wave: [vdim][key]
    __shared__ __align__(16) u16 pls[2][16 * PSTR];  // P per wave: [qrow][key]

    int wi = blockIdx.x >> 1;
    int pairid = blockIdx.x & 1;
    int wvv = threadIdx.x >> 6;        // wave id 0/1
    int hd = pairid * 2 + wvv;         // head 0..3
    int lane = threadIdx.x & 63;
    int l15 = lane & 15;
    int kg = lane >> 4;

    const u16* base = qkv + (long)wi * 256 * 224;
    u16* vtp = vt[wvv];
    u16* plp = pls[wvv];

    const bf16x8 zf = {0,0,0,0,0,0,0,0};
    const f32x4 zc = {0.f,0.f,0.f,0.f};

    for (int rd = 0; rd < 4; ++rd) {
        int tok = rd * 64 + lane;
        const u16* vp = base + tok * 224 + 128 + hd * 24;
        bf16x8 v0 = *(const bf16x8*)(vp);
        bf16x8 v1 = *(const bf16x8*)(vp + 8);
        bf16x8 v2 = *(const bf16x8*)(vp + 16);
        #pragma unroll
        for (int j = 0; j < 8; ++j) {
            vtp[(j)      * PSTR + tok] = (u16)v0[j];
            vtp[(j + 8)  * PSTR + tok] = (u16)v1[j];
            vtp[(j + 16) * PSTR + tok] = (u16)v2[j];
        }
    }

    bf16x8 kfr[16];
    #pragma unroll
    for (int nt = 0; nt < 16; ++nt) {
        int key = nt * 16 + l15;
        kfr[nt] = (kg < 2) ? *(const bf16x8*)(base + key * 224 + 64 + hd * 16 + kg * 8) : zf;
    }
    __syncthreads();

    for (int qt = 0; qt < 16; ++qt) {
        int qtok = qt * 16 + l15;
        bf16x8 qfr = (kg < 2) ? *(const bf16x8*)(base + qtok * 224 + hd * 16 + kg * 8) : zf;

        f32x4 S[16];
        #pragma unroll
        for (int nt = 0; nt < 16; ++nt)
            S[nt] = __builtin_amdgcn_mfma_f32_16x16x32_bf16(qfr, kfr[nt], zc, 0, 0, 0);

        #pragma unroll
        for (int nt = 0; nt < 16; ++nt) S[nt] *= 0.25f;

        float mx[4];
        #pragma unroll
        for (int r = 0; r < 4; ++r) {
            float m = S[0][r];
            #pragma unroll
            for (int nt = 1; nt < 16; ++nt) m = fmaxf(m, S[nt][r]);
            #pragma unroll
            for (int msk = 1; msk < 16; msk <<= 1) m = fmaxf(m, __shfl_xor(m, msk));
            mx[r] = m;
        }
        #pragma unroll
        for (int nt = 0; nt < 16; ++nt) {
            #pragma unroll
            for (int r = 0; r < 4; ++r) S[nt][r] = __expf(S[nt][r] - mx[r]);
        }
        float li[4];
        #pragma unroll
        for (int r = 0; r < 4; ++r) {
            float s = S[0][r];
            #pragma unroll
            for (int nt = 1; nt < 16; ++nt) s += S[nt][r];
            #pragma unroll
            for (int msk = 1; msk < 16; msk <<= 1) s += __shfl_xor(s, msk);
            li[r] = 1.f / s;
        }
        #pragma unroll
        for (int nt = 0; nt < 16; ++nt) {
            #pragma unroll
            for (int r = 0; r < 4; ++r) {
                int R = kg * 4 + r;
                plp[R * PSTR + nt * 16 + l15] = F2US(S[nt][r]);
            }
        }
        __syncthreads();

        f32x4 O0 = zc, O1 = zc;
        int vd1 = 16 + l15;
        #pragma unroll
        for (int ks = 0; ks < 8; ++ks) {
            bf16x8 af = *(const bf16x8*)(plp + l15 * PSTR + ks * 32 + kg * 8);
            bf16x8 b0 = *(const bf16x8*)(vtp + l15 * PSTR + ks * 32 + kg * 8);
            bf16x8 b1 = (l15 < 8) ? *(const bf16x8*)(vtp + vd1 * PSTR + ks * 32 + kg * 8) : zf;
            O0 = __builtin_amdgcn_mfma_f32_16x16x32_bf16(af, b0, O0, 0, 0, 0);
            O1 = __builtin_amdgcn_mfma_f32_16x16x32_bf16(af, b1, O1, 0, 0, 0);
        }
        #pragma unroll
        for (int r = 0; r < 4; ++r) {
            int R = kg * 4 + r;
            long tok = (long)wi * 256 + qt * 16 + R;
            attn[tok * 96 + hd * 24 + l15] = F2US(O0[r] * li[r]);
            if (l15 < 8) attn[tok * 96 + hd * 24 + 16 + l15] = F2US(O1[r] * li[r]);
        }
        __syncthreads();
    }
}

// ---------- K3: proj + residual + scatter-add (MFMA) ----------
// grid 722, block 256 (4 waves); M=256, N=96, K=96; A straight from global attn
__global__ __launch_bounds__(256) void k_proj_mfma(
    const u16* __restrict__ attn, const u16* __restrict__ wprojT,
    const float* __restrict__ x, float* __restrict__ accb)
{
    int wi = blockIdx.x;
    int b = wi / 361, r = wi % 361;
    int top = win_pos(r / 19), lf = win_pos(r % 19);
    int t = threadIdx.x;
    int wvid = t >> 6, lane = t & 63, l15 = lane & 15, kg = lane >> 4;
    const f32x4 zc = {0.f, 0.f, 0.f, 0.f};

    for (int i = 0; i < 4; ++i) {
        int rt = wvid * 4 + i;
        const u16* ap = attn + ((long)wi * 256 + rt * 16 + l15) * 96 + kg * 8;
        bf16x8 a0 = *(const bf16x8*)(ap);
        bf16x8 a1 = *(const bf16x8*)(ap + 32);
        bf16x8 a2 = *(const bf16x8*)(ap + 64);
        for (int nt = 0; nt < 6; ++nt) {
            const u16* wp = wprojT + (nt * 16 + l15) * 96 + kg * 8;
            f32x4 acc = __builtin_amdgcn_mfma_f32_16x16x32_bf16(a0, *(const bf16x8*)(wp), zc, 0, 0, 0);
            acc = __builtin_amdgcn_mfma_f32_16x16x32_bf16(a1, *(const bf16x8*)(wp + 32), acc, 0, 0, 0);
            acc = __builtin_amdgcn_mfma_f32_16x16x32_bf16(a2, *(const bf16x8*)(wp + 64), acc, 0, 0, 0);
            int c = nt * 16 + l15;
            #pragma unroll
            for (int rr = 0; rr < 4; ++rr) {
                int tok = rt * 16 + kg * 4 + rr;
                int gy = top + (tok >> 4), gx = lf + (tok & 15);
                long gi = (long)(b * 96 + c) * 65536 + (long)gy * 256 + gx;
                atomicAdd(accb + gi, acc[rr] + x[gi]);
            }
        }
    }
}

// ---------- K5: LN2 + fc1 + GELU (MFMA) ----------
// grid 2048 (64 px/block), block 256 (4 waves); M=64, N=192, K=96
#define XASTR 104
__global__ __launch_bounds__(256) void k_ln2_fc1_mfma(
    const float* __restrict__ accb,
    const float* __restrict__ n2w, const float* __restrict__ n2b,
    const u16* __restrict__ fc1T, const float* __restrict__ fc1b,
    u16* __restrict__ y1)
{
    __shared__ float xs[64 * 97];
    __shared__ __align__(16) u16 xa[64 * XASTR];
    __shared__ float mu_s[64], rs_s[64];
    int p0 = blockIdx.x * 64;
    int b = p0 >> 16, pp = p0 & 65535;
    int tid = threadIdx.x;

    for (int idx = tid; idx < 64 * 96; idx += 256) {
        int c = idx >> 6, px = idx & 63;
        int p = pp + px;
        float f = dfac(p >> 8) * dfac(p & 255);
        xs[px * 97 + c] = accb[(long)(b * 96 + c) * 65536 + p] * f;
    }
    __syncthreads();
    if (tid < 64) {
        float s = 0.f, ss = 0.f;
        for (int c = 0; c < 96; ++c) { float v = xs[tid * 97 + c]; s += v; ss += v * v; }
        float mu = s * (1.f / 96.f);
        float var = ss * (1.f / 96.f) - mu * mu;
        mu_s[tid] = mu; rs_s[tid] = rsqrtf(var + 1e-5f);
    }
    __syncthreads();
    for (int idx = tid; idx < 64 * 96; idx += 256) {
        int c = idx >> 6, px = idx & 63;
        xa[px * XASTR + c] = F2US((xs[px * 97 + c] - mu_s[px]) * rs_s[px] * n2w[c] + n2b[c]);
    }
    __syncthreads();

    int wvid = tid >> 6, lane = tid & 63, l15 = lane & 15, kg = lane >> 4;
    const f32x4 zc = {0.f, 0.f, 0.f, 0.f};
    bf16x8 a0 = *(const bf16x8*)(xa + (wvid * 16 + l15) * XASTR + 0  + kg * 8);
    bf16x8 a1 = *(const bf16x8*)(xa + (wvid * 16 + l15) * XASTR + 32 + kg * 8);
    bf16x8 a2 = *(const bf16x8*)(xa + (wvid * 16 + l15) * XASTR + 64 + kg * 8);

    for (int nt = 0; nt < 12; ++nt) {
        const u16* wp = fc1T + (nt * 16 + l15) * 96 + kg * 8;
        f32x4 acc = __builtin_amdgcn_mfma_f32_16x16x32_bf16(a0, *(const bf16x8*)(wp), zc, 0, 0, 0);
        acc = __builtin_amdgcn_mfma_f32_16x16x32_bf16(a1, *(const bf16x8*)(wp + 32), acc, 0, 0, 0);
        acc = __builtin_amdgcn_mfma_f32_16x16x32_bf16(a2, *(const bf16x8*)(wp + 64), acc, 0, 0, 0);
        int m = nt * 16 + l15;
        float bb = fc1b[m];
        ushort4 pk;
        pk.x = F2US(gelu_exact(acc[0] + bb));
        pk.y = F2US(gelu_exact(acc[1] + bb));
        pk.z = F2US(gelu_exact(acc[2] + bb));
        pk.w = F2US(gelu_exact(acc[3] + bb));
        *(ushort4*)(y1 + (long)(b * 192 + m) * 65536 + pp + wvid * 16 + kg * 4) = pk;
    }
}

// ---------- K6: depthwise 5x5 conv + GELU + add -> y2 ----------
// grid 512 (b x 16x16 tiles of 16x16 px), block 256
__global__ __launch_bounds__(256) void k_dwconv(
    const u16* __restrict__ y1, const float* __restrict__ dww, const float* __restrict__ dwb,
    u16* __restrict__ y2)
{
    __shared__ float tile[20 * 20];
    __shared__ float wsm[25];
    int blk = blockIdx.x;
    int b = blk >> 8; int t8 = blk & 255;
    int by = (t8 >> 4) << 4, bx = (t8 & 15) << 4;
    int tid = threadIdx.x;
    int ty = tid >> 4, tx = tid & 15;
    int gy = by + ty, gx = bx + tx;

    for (int m = 0; m < 192; ++m) {
        const u16* plane = y1 + (long)(b * 192 + m) * 65536;
        if (tid < 25) wsm[tid] = dww[m * 25 + tid];
        for (int idx = tid; idx < 400; idx += 256) {
            int ly = idx / 20, lx = idx - ly * 20;
            int sy = by + ly - 2, sx = bx + lx - 2;
            float v = 0.f;
            if (sy >= 0 && sy < 256 && sx >= 0 && sx < 256) v = US2F(plane[sy * 256 + sx]);
            tile[idx] = v;
        }
        __syncthreads();
        float acc = 0.f;
        #pragma unroll
        for (int ky = 0; ky < 5; ++ky)
            #pragma unroll
            for (int kx = 0; kx < 5; ++kx)
                acc += tile[(ty + ky) * 20 + tx + kx] * wsm[ky * 5 + kx];
        float center = tile[(ty + 2) * 20 + tx + 2];
        float v = center + gelu_exact(acc + dwb[m]);
        y2[(long)(b * 192 + m) * 65536 + gy * 256 + gx] = F2US(v);
        __syncthreads();
    }
}

// ---------- K7: fc2 + bias + residual (MFMA) ----------
// grid 2048 (64 px/block), block 256 (4 waves); M=64, N=96, K=192
#define Y2STR 200
__global__ __launch_bounds__(256) void k_fc2_mfma(
    const u16* __restrict__ y2, const u16* __restrict__ fc2T, const float* __restrict__ fc2b,
    const float* __restrict__ accb, float* __restrict__ out)
{
    __shared__ __align__(16) u16 ys2[64 * Y2STR];
    int p0 = blockIdx.x * 64;
    int b = p0 >> 16, pp = p0 & 65535;
    int tid = threadIdx.x;
    for (int idx = tid; idx < 64 * 192; idx += 256) {
        int m = idx >> 6, px = idx & 63;
        ys2[px * Y2STR + m] = y2[(long)(b * 192 + m) * 65536 + pp + px];
    }
    __syncthreads();

    int wvid = tid >> 6, lane = tid & 63, l15 = lane & 15, kg = lane >> 4;
    const f32x4 zc = {0.f, 0.f, 0.f, 0.f};
    bf16x8 af[6];
    #pragma unroll
    for (int ks = 0; ks < 6; ++ks)
        af[ks] = *(const bf16x8*)(ys2 + (wvid * 16 + l15) * Y2STR + ks * 32 + kg * 8);

    int pxb = pp + wvid * 16 + kg * 4;
    float fy = dfac((pp + wvid * 16) >> 8);
    float f0 = fy * dfac((pxb + 0) & 255);
    float f1 = fy * dfac((pxb + 1) & 255);
    float f2 = fy * dfac((pxb + 2) & 255);
    float f3 = fy * dfac((pxb + 3) & 255);

    for (int nt = 0; nt < 6; ++nt) {
        const u16* wp = fc2T + (nt * 16 + l15) * 192 + kg * 8;
        f32x4 acc = zc;
        #pragma unroll
        for (int ks = 0; ks < 6; ++ks)
            acc = __builtin_amdgcn_mfma_f32_16x16x32_bf16(af[ks], *(const bf16x8*)(wp + ks * 32), acc, 0, 0, 0);
        int c = nt * 16 + l15;
        long gbase = (long)(b * 96 + c) * 65536 + pxb;
        float4 av = *(const float4*)(accb + gbase);
        float4 res;
        float bb = fc2b[c];
        res.x = acc[0] + bb + av.x * f0;
        res.y = acc[1] + bb + av.y * f1;
        res.z = acc[2] + bb + av.z * f2;
        res.w = acc[3] + bb + av.w * f3;
        *(float4*)(out + gbase) = res;
    }
}

extern "C" void kernel_launch(void* const* d_in, const int* in_sizes, int n_in,
                              void* d_out, int out_size, void* d_ws, size_t ws_size,
                              hipStream_t stream)
{
    const float* x     = (const float*)d_in[0];
    const float* n1w   = (const float*)d_in[1];
    const float* n1b   = (const float*)d_in[2];
    const float* wq    = (const float*)d_in[3];
    const float* wk    = (const float*)d_in[4];
    const float* wv    = (const float*)d_in[5];
    const float* wproj = (const float*)d_in[6];
    const float* n2w   = (const float*)d_in[7];
    const float* n2b   = (const float*)d_in[8];
    const float* fc1w  = (const float*)d_in[9];
    const float* fc1b  = (const float*)d_in[10];
    const float* dww   = (const float*)d_in[11];
    const float* dwb   = (const float*)d_in[12];
    const float* fc2w  = (const float*)d_in[13];
    const float* fc2b  = (const float*)d_in[14];

    char* ws = (char*)d_ws;
    float* accb = (float*)ws;                       // [0, 50331648) fp32 acc
    u16* qkv  = (u16*)(ws + 50331648);              // [50.3M, 133.1M) bf16 (722,256,224)
    u16* attn = (u16*)(ws + 133136384);             // [133.1M, 168.6M) bf16 (722,256,96)
    u16* y1   = (u16*)(ws + 50331648);              // reuse qkv region (dead after attention+proj... y1 written after proj)
    u16* y2   = (u16*)(ws + 100663296);             // [100.7M, 151.0M) (overlaps dead qkv tail + dead attn head)
    u16* wT   = (u16*)(ws + 168624128);             // [168.6M, +135168) bf16 transposed weights
    u16* wqkvT  = wT;
    u16* wprojT = wT + 21504;
    u16* fc1T   = wT + 30720;
    u16* fc2T   = wT + 49152;
    float* out = (float*)d_out;

    k_prep<<<264, 256, 0, stream>>>(wq, wk, wv, wproj, fc1w, fc2w, wT);
    kzero<<<12288, 256, 0, stream>>>(accb, 3145728);
    k_ln_qkv_mfma<<<722, 256, 0, stream>>>(x, n1w, n1b, wqkvT, qkv);
    k_attn_mfma<<<1444, 128, 0, stream>>>(qkv, attn);
    k_proj_mfma<<<722, 256, 0, stream>>>(attn, wprojT, x, accb);
    k_ln2_fc1_mfma<<<2048, 256, 0, stream>>>(accb, n2w, n2b, fc1T, fc1b, y1);
    k_dwconv<<<512, 256, 0, stream>>>(y1, dww, dwb, y2);
    k_fc2_mfma<<<2048, 256, 0, stream>>>(y2, fc2T, fc2b, accb, out);
}

// Round 6
// 733.811 us; speedup vs baseline: 2.2063x; 1.4213x over previous
//
#include <hip/hip_runtime.h>

typedef unsigned short u16;
typedef unsigned int u32;
typedef __attribute__((ext_vector_type(8))) short bf16x8;
typedef __attribute__((ext_vector_type(4))) float f32x4;

// ---------- helpers ----------
__device__ __forceinline__ float US2F(u16 u) {
    return __uint_as_float(((u32)u) << 16);
}
__device__ __forceinline__ u16 F2US(float f) {   // round-to-nearest-even bf16
    u32 u = __float_as_uint(f);
    u32 rounding = 0x7fffu + ((u >> 16) & 1u);
    u += rounding;
    return (u16)(u >> 16);
}

__device__ __forceinline__ int win_pos(int i) { return (i == 18) ? 240 : 14 * i; }
__device__ __forceinline__ float gelu_exact(float x) {
    return 0.5f * x * (1.0f + erff(x * 0.7071067811865475f));
}

// ---------- Kprep: transpose + bf16-cast all GEMM weights ----------
// wT element layout: [0,21504) wqkvT[224][96]; [21504,30720) wprojT[96][96];
// [30720,49152) fc1T[192][96]; [49152,67584) fc2T[96][192]
__global__ __launch_bounds__(256) void k_prep(
    const float* __restrict__ wq, const float* __restrict__ wk, const float* __restrict__ wv,
    const float* __restrict__ wproj, const float* __restrict__ fc1w, const float* __restrict__ fc2w,
    u16* __restrict__ wT)
{
    int i = blockIdx.x * 256 + threadIdx.x;
    if (i < 21504) {
        int m = i / 96, c = i % 96;
        float v = (m < 64) ? wq[c * 64 + m] : ((m < 128) ? wk[c * 64 + m - 64] : wv[c * 96 + m - 128]);
        wT[i] = F2US(v);
    } else if (i < 30720) {
        int j = i - 21504; int n = j / 96, k = j % 96;
        wT[i] = F2US(wproj[k * 96 + n]);
    } else if (i < 49152) {
        int j = i - 30720; int n = j / 96, k = j % 96;
        wT[i] = F2US(fc1w[k * 192 + n]);
    } else if (i < 67584) {
        int j = i - 49152; int n = j / 192, k = j % 192;
        wT[i] = F2US(fc2w[k * 96 + n]);
    }
}

// ---------- K1: window gather + LN1 + QKV (MFMA) ----------
// grid 722, block 256 (4 waves); M=256 tokens, N=224, K=96
#define YSTR 104
__global__ __launch_bounds__(256) void k_ln_qkv_mfma(
    const float* __restrict__ x, const float* __restrict__ n1w, const float* __restrict__ n1b,
    const u16* __restrict__ wqkvT, u16* __restrict__ qkv)
{
    __shared__ __align__(16) u16 ys[256 * YSTR];
    int wi = blockIdx.x;
    int b = wi / 361, r = wi % 361;
    int top = win_pos(r / 19), lf = win_pos(r % 19);
    int t = threadIdx.x;
    int gy = top + (t >> 4), gx = lf + (t & 15);
    const float* xp = x + (long)b * 96 * 65536 + (long)gy * 256 + gx;

    float s = 0.f, ss = 0.f;
    for (int c = 0; c < 96; ++c) {
        float v = xp[(long)c * 65536];
        ys[t * YSTR + c] = F2US(v);
        s += v; ss += v * v;
    }
    float mu = s * (1.f / 96.f);
    float var = ss * (1.f / 96.f) - mu * mu;
    float rstd = rsqrtf(var + 1e-5f);
    for (int c = 0; c < 96; ++c) {
        float v = US2F(ys[t * YSTR + c]);
        ys[t * YSTR + c] = F2US((v - mu) * rstd * n1w[c] + n1b[c]);
    }
    __syncthreads();

    int wvid = t >> 6, lane = t & 63, l15 = lane & 15, kg = lane >> 4;
    const f32x4 zc = {0.f, 0.f, 0.f, 0.f};

    for (int i = 0; i < 4; ++i) {
        int rt = wvid * 4 + i;
        bf16x8 a0 = *(const bf16x8*)(ys + (rt * 16 + l15) * YSTR + 0  + kg * 8);
        bf16x8 a1 = *(const bf16x8*)(ys + (rt * 16 + l15) * YSTR + 32 + kg * 8);
        bf16x8 a2 = *(const bf16x8*)(ys + (rt * 16 + l15) * YSTR + 64 + kg * 8);
        for (int nt = 0; nt < 14; ++nt) {
            const u16* wp = wqkvT + (nt * 16 + l15) * 96 + kg * 8;
            f32x4 acc = __builtin_amdgcn_mfma_f32_16x16x32_bf16(a0, *(const bf16x8*)(wp), zc, 0, 0, 0);
            acc = __builtin_amdgcn_mfma_f32_16x16x32_bf16(a1, *(const bf16x8*)(wp + 32), acc, 0, 0, 0);
            acc = __builtin_amdgcn_mfma_f32_16x16x32_bf16(a2, *(const bf16x8*)(wp + 64), acc, 0, 0, 0);
            u16* op = qkv + ((long)wi * 256 + rt * 16 + kg * 4) * 224 + nt * 16 + l15;
            #pragma unroll
            for (int rr = 0; rr < 4; ++rr) op[rr * 224] = F2US(acc[rr]);
        }
    }
}

// ---------- K2: MFMA flash attention ----------
// grid 722*2 (window x head-pair), block 128 (2 waves, wave = one head)
#define PSTR 264
__global__ __launch_bounds__(128) void k_attn_mfma(const u16* __restrict__ qkv, u16* __restrict__ attn)
{
    __shared__ __align__(16) u16 vt[2][24 * PSTR];
    __shared__ __align__(16) u16 pls[2][16 * PSTR];

    int wi = blockIdx.x >> 1;
    int pairid = blockIdx.x & 1;
    int wvv = threadIdx.x >> 6;
    int hd = pairid * 2 + wvv;
    int lane = threadIdx.x & 63;
    int l15 = lane & 15;
    int kg = lane >> 4;

    const u16* base = qkv + (long)wi * 256 * 224;
    u16* vtp = vt[wvv];
    u16* plp = pls[wvv];

    const bf16x8 zf = {0,0,0,0,0,0,0,0};
    const f32x4 zc = {0.f,0.f,0.f,0.f};

    for (int rd = 0; rd < 4; ++rd) {
        int tok = rd * 64 + lane;
        const u16* vp = base + tok * 224 + 128 + hd * 24;
        bf16x8 v0 = *(const bf16x8*)(vp);
        bf16x8 v1 = *(const bf16x8*)(vp + 8);
        bf16x8 v2 = *(const bf16x8*)(vp + 16);
        #pragma unroll
        for (int j = 0; j < 8; ++j) {
            vtp[(j)      * PSTR + tok] = (u16)v0[j];
            vtp[(j + 8)  * PSTR + tok] = (u16)v1[j];
            vtp[(j + 16) * PSTR + tok] = (u16)v2[j];
        }
    }

    bf16x8 kfr[16];
    #pragma unroll
    for (int nt = 0; nt < 16; ++nt) {
        int key = nt * 16 + l15;
        kfr[nt] = (kg < 2) ? *(const bf16x8*)(base + key * 224 + 64 + hd * 16 + kg * 8) : zf;
    }
    __syncthreads();

    for (int qt = 0; qt < 16; ++qt) {
        int qtok = qt * 16 + l15;
        bf16x8 qfr = (kg < 2) ? *(const bf16x8*)(base + qtok * 224 + hd * 16 + kg * 8) : zf;

        f32x4 S[16];
        #pragma unroll
        for (int nt = 0; nt < 16; ++nt)
            S[nt] = __builtin_amdgcn_mfma_f32_16x16x32_bf16(qfr, kfr[nt], zc, 0, 0, 0);

        #pragma unroll
        for (int nt = 0; nt < 16; ++nt) S[nt] *= 0.25f;

        float mx[4];
        #pragma unroll
        for (int r = 0; r < 4; ++r) {
            float m = S[0][r];
            #pragma unroll
            for (int nt = 1; nt < 16; ++nt) m = fmaxf(m, S[nt][r]);
            #pragma unroll
            for (int msk = 1; msk < 16; msk <<= 1) m = fmaxf(m, __shfl_xor(m, msk));
            mx[r] = m;
        }
        #pragma unroll
        for (int nt = 0; nt < 16; ++nt) {
            #pragma unroll
            for (int r = 0; r < 4; ++r) S[nt][r] = __expf(S[nt][r] - mx[r]);
        }
        float li[4];
        #pragma unroll
        for (int r = 0; r < 4; ++r) {
            float s = S[0][r];
            #pragma unroll
            for (int nt = 1; nt < 16; ++nt) s += S[nt][r];
            #pragma unroll
            for (int msk = 1; msk < 16; msk <<= 1) s += __shfl_xor(s, msk);
            li[r] = 1.f / s;
        }
        #pragma unroll
        for (int nt = 0; nt < 16; ++nt) {
            #pragma unroll
            for (int r = 0; r < 4; ++r) {
                int R = kg * 4 + r;
                plp[R * PSTR + nt * 16 + l15] = F2US(S[nt][r]);
            }
        }
        __syncthreads();

        f32x4 O0 = zc, O1 = zc;
        int vd1 = 16 + l15;
        #pragma unroll
        for (int ks = 0; ks < 8; ++ks) {
            bf16x8 af = *(const bf16x8*)(plp + l15 * PSTR + ks * 32 + kg * 8);
            bf16x8 b0 = *(const bf16x8*)(vtp + l15 * PSTR + ks * 32 + kg * 8);
            bf16x8 b1 = (l15 < 8) ? *(const bf16x8*)(vtp + vd1 * PSTR + ks * 32 + kg * 8) : zf;
            O0 = __builtin_amdgcn_mfma_f32_16x16x32_bf16(af, b0, O0, 0, 0, 0);
            O1 = __builtin_amdgcn_mfma_f32_16x16x32_bf16(af, b1, O1, 0, 0, 0);
        }
        #pragma unroll
        for (int r = 0; r < 4; ++r) {
            int R = kg * 4 + r;
            long tok = (long)wi * 256 + qt * 16 + R;
            attn[tok * 96 + hd * 24 + l15] = F2US(O0[r] * li[r]);
            if (l15 < 8) attn[tok * 96 + hd * 24 + 16 + l15] = F2US(O1[r] * li[r]);
        }
        __syncthreads();
    }
}

// ---------- K3: proj GEMM -> dense per-window wout[wi][c][token] (no atomics) ----------
// grid 722, block 256 (4 waves); M=256, N=96, K=96
#define WOSTR 264   // LDS row stride (u16): 528B rows, 16B-aligned
__global__ __launch_bounds__(256) void k_proj_mfma(
    const u16* __restrict__ attn, const u16* __restrict__ wprojT,
    u16* __restrict__ wout)
{
    __shared__ __align__(16) u16 cs[96 * WOSTR];
    int wi = blockIdx.x;
    int t = threadIdx.x;
    int wvid = t >> 6, lane = t & 63, l15 = lane & 15, kg = lane >> 4;
    const f32x4 zc = {0.f, 0.f, 0.f, 0.f};

    for (int i = 0; i < 4; ++i) {
        int rt = wvid * 4 + i;
        const u16* ap = attn + ((long)wi * 256 + rt * 16 + l15) * 96 + kg * 8;
        bf16x8 a0 = *(const bf16x8*)(ap);
        bf16x8 a1 = *(const bf16x8*)(ap + 32);
        bf16x8 a2 = *(const bf16x8*)(ap + 64);
        for (int nt = 0; nt < 6; ++nt) {
            const u16* wp = wprojT + (nt * 16 + l15) * 96 + kg * 8;
            f32x4 acc = __builtin_amdgcn_mfma_f32_16x16x32_bf16(a0, *(const bf16x8*)(wp), zc, 0, 0, 0);
            acc = __builtin_amdgcn_mfma_f32_16x16x32_bf16(a1, *(const bf16x8*)(wp + 32), acc, 0, 0, 0);
            acc = __builtin_amdgcn_mfma_f32_16x16x32_bf16(a2, *(const bf16x8*)(wp + 64), acc, 0, 0, 0);
            int c = nt * 16 + l15;
            #pragma unroll
            for (int rr = 0; rr < 4; ++rr) {
                int tok = rt * 16 + kg * 4 + rr;
                cs[c * WOSTR + tok] = F2US(acc[rr]);
            }
        }
    }
    __syncthreads();
    // coalesced write-out: 96 rows x 256 tokens, 16B segments
    u16* wo = wout + (long)wi * 24576;
    for (int seg = t; seg < 3072; seg += 256) {
        int c = seg >> 5, t8 = (seg & 31) << 3;
        *(bf16x8*)(wo + c * 256 + t8) = *(const bf16x8*)(cs + c * WOSTR + t8);
    }
}

// ---------- K4: gather overlapping windows -> x2 (factor pre-applied) ----------
// grid b*96*256 (one block per (b,c,y) row), block 256 (thread = x)
__global__ __launch_bounds__(256) void k_gather(
    const u16* __restrict__ wout, const float* __restrict__ x, float* __restrict__ accb)
{
    int blk = blockIdx.x;
    int y = blk & 255;
    int c = (blk >> 8) % 96;
    int b = blk / (96 * 256);
    int xx = threadIdx.x;

    // y-covering windows (block-uniform)
    int iyl[2]; int ny = 0;
    {
        int c1 = min(17, y / 14), c0 = c1 - 1;
        if (c0 >= 0 && y >= 14 * c0 && y < 14 * c0 + 16) iyl[ny++] = c0;
        if (y >= 14 * c1 && y < 14 * c1 + 16) iyl[ny++] = c1;
        if (y >= 240) iyl[ny++] = 18;
    }
    // x-covering windows (per-thread)
    int ixl[2]; int nx = 0;
    {
        int c1 = min(17, xx / 14), c0 = c1 - 1;
        if (c0 >= 0 && xx >= 14 * c0 && xx < 14 * c0 + 16) ixl[nx++] = c0;
        if (xx >= 14 * c1 && xx < 14 * c1 + 16) ixl[nx++] = c1;
        if (xx >= 240) ixl[nx++] = 18;
    }

    long p = (long)(b * 96 + c) * 65536 + y * 256 + xx;
    float v = (float)(ny * nx) * x[p];
    for (int a = 0; a < ny; ++a) {
        int ty = win_pos(iyl[a]);
        int rowoff = (y - ty) * 16;
        for (int e = 0; e < nx; ++e) {
            int tx = win_pos(ixl[e]);
            int wi = b * 361 + iyl[a] * 19 + ixl[e];
            v += US2F(wout[(long)wi * 24576 + c * 256 + rowoff + (xx - tx)]);
        }
    }
    float f = ((ny == 2) ? 0.5f : 1.f) * ((nx == 2) ? 0.5f : 1.f);
    accb[p] = v * f;
}

// ---------- K5: LN2 + fc1 + GELU (MFMA) ----------
// grid 2048 (64 px/block), block 256 (4 waves); M=64, N=192, K=96
#define XASTR 104
__global__ __launch_bounds__(256) void k_ln2_fc1_mfma(
    const float* __restrict__ accb,
    const float* __restrict__ n2w, const float* __restrict__ n2b,
    const u16* __restrict__ fc1T, const float* __restrict__ fc1b,
    u16* __restrict__ y1)
{
    __shared__ float xs[64 * 97];
    __shared__ __align__(16) u16 xa[64 * XASTR];
    __shared__ float mu_s[64], rs_s[64];
    int p0 = blockIdx.x * 64;
    int b = p0 >> 16, pp = p0 & 65535;
    int tid = threadIdx.x;

    for (int idx = tid; idx < 64 * 96; idx += 256) {
        int c = idx >> 6, px = idx & 63;
        xs[px * 97 + c] = accb[(long)(b * 96 + c) * 65536 + pp + px];
    }
    __syncthreads();
    if (tid < 64) {
        float s = 0.f, ss = 0.f;
        for (int c = 0; c < 96; ++c) { float v = xs[tid * 97 + c]; s += v; ss += v * v; }
        float mu = s * (1.f / 96.f);
        float var = ss * (1.f / 96.f) - mu * mu;
        mu_s[tid] = mu; rs_s[tid] = rsqrtf(var + 1e-5f);
    }
    __syncthreads();
    for (int idx = tid; idx < 64 * 96; idx += 256) {
        int c = idx >> 6, px = idx & 63;
        xa[px * XASTR + c] = F2US((xs[px * 97 + c] - mu_s[px]) * rs_s[px] * n2w[c] + n2b[c]);
    }
    __syncthreads();

    int wvid = tid >> 6, lane = tid & 63, l15 = lane & 15, kg = lane >> 4;
    const f32x4 zc = {0.f, 0.f, 0.f, 0.f};
    bf16x8 a0 = *(const bf16x8*)(xa + (wvid * 16 + l15) * XASTR + 0  + kg * 8);
    bf16x8 a1 = *(const bf16x8*)(xa + (wvid * 16 + l15) * XASTR + 32 + kg * 8);
    bf16x8 a2 = *(const bf16x8*)(xa + (wvid * 16 + l15) * XASTR + 64 + kg * 8);

    for (int nt = 0; nt < 12; ++nt) {
        const u16* wp = fc1T + (nt * 16 + l15) * 96 + kg * 8;
        f32x4 acc = __builtin_amdgcn_mfma_f32_16x16x32_bf16(a0, *(const bf16x8*)(wp), zc, 0, 0, 0);
        acc = __builtin_amdgcn_mfma_f32_16x16x32_bf16(a1, *(const bf16x8*)(wp + 32), acc, 0, 0, 0);
        acc = __builtin_amdgcn_mfma_f32_16x16x32_bf16(a2, *(const bf16x8*)(wp + 64), acc, 0, 0, 0);
        int m = nt * 16 + l15;
        float bb = fc1b[m];
        ushort4 pk;
        pk.x = F2US(gelu_exact(acc[0] + bb));
        pk.y = F2US(gelu_exact(acc[1] + bb));
        pk.z = F2US(gelu_exact(acc[2] + bb));
        pk.w = F2US(gelu_exact(acc[3] + bb));
        *(ushort4*)(y1 + (long)(b * 192 + m) * 65536 + pp + wvid * 16 + kg * 4) = pk;
    }
}

// ---------- K6: depthwise 5x5 conv + GELU + add -> y2 ----------
// grid 512 (b x 16x16 tiles of 16x16 px), block 256
__global__ __launch_bounds__(256) void k_dwconv(
    const u16* __restrict__ y1, const float* __restrict__ dww, const float* __restrict__ dwb,
    u16* __restrict__ y2)
{
    __shared__ float tile[20 * 20];
    __shared__ float wsm[25];
    int blk = blockIdx.x;
    int b = blk >> 8; int t8 = blk & 255;
    int by = (t8 >> 4) << 4, bx = (t8 & 15) << 4;
    int tid = threadIdx.x;
    int ty = tid >> 4, tx = tid & 15;
    int gy = by + ty, gx = bx + tx;

    for (int m = 0; m < 192; ++m) {
        const u16* plane = y1 + (long)(b * 192 + m) * 65536;
        if (tid < 25) wsm[tid] = dww[m * 25 + tid];
        for (int idx = tid; idx < 400; idx += 256) {
            int ly = idx / 20, lx = idx - ly * 20;
            int sy = by + ly - 2, sx = bx + lx - 2;
            float v = 0.f;
            if (sy >= 0 && sy < 256 && sx >= 0 && sx < 256) v = US2F(plane[sy * 256 + sx]);
            tile[idx] = v;
        }
        __syncthreads();
        float acc = 0.f;
        #pragma unroll
        for (int ky = 0; ky < 5; ++ky)
            #pragma unroll
            for (int kx = 0; kx < 5; ++kx)
                acc += tile[(ty + ky) * 20 + tx + kx] * wsm[ky * 5 + kx];
        float center = tile[(ty + 2) * 20 + tx + 2];
        float v = center + gelu_exact(acc + dwb[m]);
        y2[(long)(b * 192 + m) * 65536 + gy * 256 + gx] = F2US(v);
        __syncthreads();
    }
}

// ---------- K7: fc2 + bias + residual (MFMA) ----------
// grid 2048 (64 px/block), block 256 (4 waves); M=64, N=96, K=192
#define Y2STR 200
__global__ __launch_bounds__(256) void k_fc2_mfma(
    const u16* __restrict__ y2, const u16* __restrict__ fc2T, const float* __restrict__ fc2b,
    const float* __restrict__ accb, float* __restrict__ out)
{
    __shared__ __align__(16) u16 ys2[64 * Y2STR];
    int p0 = blockIdx.x * 64;
    int b = p0 >> 16, pp = p0 & 65535;
    int tid = threadIdx.x;
    for (int idx = tid; idx < 64 * 192; idx += 256) {
        int m = idx >> 6, px = idx & 63;
        ys2[px * Y2STR + m] = y2[(long)(b * 192 + m) * 65536 + pp + px];
    }
    __syncthreads();

    int wvid = tid >> 6, lane = tid & 63, l15 = lane & 15, kg = lane >> 4;
    const f32x4 zc = {0.f, 0.f, 0.f, 0.f};
    bf16x8 af[6];
    #pragma unroll
    for (int ks = 0; ks < 6; ++ks)
        af[ks] = *(const bf16x8*)(ys2 + (wvid * 16 + l15) * Y2STR + ks * 32 + kg * 8);

    int pxb = pp + wvid * 16 + kg * 4;

    for (int nt = 0; nt < 6; ++nt) {
        const u16* wp = fc2T + (nt * 16 + l15) * 192 + kg * 8;
        f32x4 acc = zc;
        #pragma unroll
        for (int ks = 0; ks < 6; ++ks)
            acc = __builtin_amdgcn_mfma_f32_16x16x32_bf16(af[ks], *(const bf16x8*)(wp + ks * 32), acc, 0, 0, 0);
        int c = nt * 16 + l15;
        long gbase = (long)(b * 96 + c) * 65536 + pxb;
        float4 av = *(const float4*)(accb + gbase);
        float4 res;
        float bb = fc2b[c];
        res.x = acc[0] + bb + av.x;
        res.y = acc[1] + bb + av.y;
        res.z = acc[2] + bb + av.z;
        res.w = acc[3] + bb + av.w;
        *(float4*)(out + gbase) = res;
    }
}

extern "C" void kernel_launch(void* const* d_in, const int* in_sizes, int n_in,
                              void* d_out, int out_size, void* d_ws, size_t ws_size,
                              hipStream_t stream)
{
    const float* x     = (const float*)d_in[0];
    const float* n1w   = (const float*)d_in[1];
    const float* n1b   = (const float*)d_in[2];
    const float* wq    = (const float*)d_in[3];
    const float* wk    = (const float*)d_in[4];
    const float* wv    = (const float*)d_in[5];
    const float* wproj = (const float*)d_in[6];
    const float* n2w   = (const float*)d_in[7];
    const float* n2b   = (const float*)d_in[8];
    const float* fc1w  = (const float*)d_in[9];
    const float* fc1b  = (const float*)d_in[10];
    const float* dww   = (const float*)d_in[11];
    const float* dwb   = (const float*)d_in[12];
    const float* fc2w  = (const float*)d_in[13];
    const float* fc2b  = (const float*)d_in[14];

    char* ws = (char*)d_ws;
    // memory map (R4-proven footprint, peak 168,759,296 B):
    //   accb fp32 [0, 50.3M)          k_gather -> ln2_fc1, fc2
    //   qkv  bf16 [50.3M, 133.1M)     k_ln_qkv -> k_attn        (dead after attn)
    //   attn bf16 [133.1M, 168.6M)    k_attn -> k_proj          (dead after proj)
    //   wout bf16 [50.3M, 85.8M)      k_proj -> k_gather        (reuses dead qkv head; dead after gather)
    //   y1   bf16 [100.7M, 151.0M)    ln2_fc1 -> dwconv         (dead qkv tail + dead attn head; clears wout)
    //   y2   bf16 [50.3M, 100.7M)     dwconv -> fc2             (dead wout + dead qkv; below y1)
    //   wT   bf16 [168.6M, +135168)   k_prep -> all GEMMs
    float* accb = (float*)ws;
    u16* qkv  = (u16*)(ws + 50331648);
    u16* attn = (u16*)(ws + 133136384);
    u16* wout = (u16*)(ws + 50331648);
    u16* y1   = (u16*)(ws + 100663296);
    u16* y2   = (u16*)(ws + 50331648);
    u16* wT   = (u16*)(ws + 168624128);
    u16* wqkvT  = wT;
    u16* wprojT = wT + 21504;
    u16* fc1T   = wT + 30720;
    u16* fc2T   = wT + 49152;
    float* out = (float*)d_out;

    k_prep<<<264, 256, 0, stream>>>(wq, wk, wv, wproj, fc1w, fc2w, wT);
    k_ln_qkv_mfma<<<722, 256, 0, stream>>>(x, n1w, n1b, wqkvT, qkv);
    k_attn_mfma<<<1444, 128, 0, stream>>>(qkv, attn);
    k_proj_mfma<<<722, 256, 0, stream>>>(attn, wprojT, wout);
    k_gather<<<49152, 256, 0, stream>>>(wout, x, accb);
    k_ln2_fc1_mfma<<<2048, 256, 0, stream>>>(accb, n2w, n2b, fc1T, fc1b, y1);
    k_dwconv<<<512, 256, 0, stream>>>(y1, dww, dwb, y2);
    k_fc2_mfma<<<2048, 256, 0, stream>>>(y2, fc2T, fc2b, accb, out);
}

// Round 7
// 531.168 us; speedup vs baseline: 3.0481x; 1.3815x over previous
//
#include <hip/hip_runtime.h>

typedef unsigned short u16;
typedef unsigned int u32;
typedef __attribute__((ext_vector_type(8))) short bf16x8;
typedef __attribute__((ext_vector_type(4))) float f32x4;

// ---------- helpers ----------
__device__ __forceinline__ float US2F(u16 u) {
    return __uint_as_float(((u32)u) << 16);
}
__device__ __forceinline__ u16 F2US(float f) {   // round-to-nearest-even bf16
    u32 u = __float_as_uint(f);
    u32 rounding = 0x7fffu + ((u >> 16) & 1u);
    u += rounding;
    return (u16)(u >> 16);
}

__device__ __forceinline__ int win_pos(int i) { return (i == 18) ? 240 : 14 * i; }
__device__ __forceinline__ float gelu_exact(float x) {
    return 0.5f * x * (1.0f + erff(x * 0.7071067811865475f));
}

// ---------- Kprep: transpose + bf16-cast all GEMM weights ----------
// wT element layout: [0,21504) wqkvT[224][96]; [21504,30720) wprojT[96][96];
// [30720,49152) fc1T[192][96]; [49152,67584) fc2T[96][192]
__global__ __launch_bounds__(256) void k_prep(
    const float* __restrict__ wq, const float* __restrict__ wk, const float* __restrict__ wv,
    const float* __restrict__ wproj, const float* __restrict__ fc1w, const float* __restrict__ fc2w,
    u16* __restrict__ wT)
{
    int i = blockIdx.x * 256 + threadIdx.x;
    if (i < 21504) {
        int m = i / 96, c = i % 96;
        float v = (m < 64) ? wq[c * 64 + m] : ((m < 128) ? wk[c * 64 + m - 64] : wv[c * 96 + m - 128]);
        wT[i] = F2US(v);
    } else if (i < 30720) {
        int j = i - 21504; int n = j / 96, k = j % 96;
        wT[i] = F2US(wproj[k * 96 + n]);
    } else if (i < 49152) {
        int j = i - 30720; int n = j / 96, k = j % 96;
        wT[i] = F2US(fc1w[k * 192 + n]);
    } else if (i < 67584) {
        int j = i - 49152; int n = j / 192, k = j % 192;
        wT[i] = F2US(fc2w[k * 96 + n]);
    }
}

// ---------- K1: window gather + LN1 + QKV (MFMA) ----------
// grid 722, block 256 (4 waves); M=256 tokens, N=224, K=96
#define YSTR 104
__global__ __launch_bounds__(256) void k_ln_qkv_mfma(
    const float* __restrict__ x, const float* __restrict__ n1w, const float* __restrict__ n1b,
    const u16* __restrict__ wqkvT, u16* __restrict__ qkv)
{
    __shared__ __align__(16) u16 ys[256 * YSTR];
    int wi = blockIdx.x;
    int b = wi / 361, r = wi % 361;
    int top = win_pos(r / 19), lf = win_pos(r % 19);
    int t = threadIdx.x;
    int gy = top + (t >> 4), gx = lf + (t & 15);
    const float* xp = x + (long)b * 96 * 65536 + (long)gy * 256 + gx;

    float s = 0.f, ss = 0.f;
    for (int c = 0; c < 96; ++c) {
        float v = xp[(long)c * 65536];
        ys[t * YSTR + c] = F2US(v);
        s += v; ss += v * v;
    }
    float mu = s * (1.f / 96.f);
    float var = ss * (1.f / 96.f) - mu * mu;
    float rstd = rsqrtf(var + 1e-5f);
    for (int c = 0; c < 96; ++c) {
        float v = US2F(ys[t * YSTR + c]);
        ys[t * YSTR + c] = F2US((v - mu) * rstd * n1w[c] + n1b[c]);
    }
    __syncthreads();

    int wvid = t >> 6, lane = t & 63, l15 = lane & 15, kg = lane >> 4;
    const f32x4 zc = {0.f, 0.f, 0.f, 0.f};

    for (int i = 0; i < 4; ++i) {
        int rt = wvid * 4 + i;
        bf16x8 a0 = *(const bf16x8*)(ys + (rt * 16 + l15) * YSTR + 0  + kg * 8);
        bf16x8 a1 = *(const bf16x8*)(ys + (rt * 16 + l15) * YSTR + 32 + kg * 8);
        bf16x8 a2 = *(const bf16x8*)(ys + (rt * 16 + l15) * YSTR + 64 + kg * 8);
        for (int nt = 0; nt < 14; ++nt) {
            const u16* wp = wqkvT + (nt * 16 + l15) * 96 + kg * 8;
            f32x4 acc = __builtin_amdgcn_mfma_f32_16x16x32_bf16(a0, *(const bf16x8*)(wp), zc, 0, 0, 0);
            acc = __builtin_amdgcn_mfma_f32_16x16x32_bf16(a1, *(const bf16x8*)(wp + 32), acc, 0, 0, 0);
            acc = __builtin_amdgcn_mfma_f32_16x16x32_bf16(a2, *(const bf16x8*)(wp + 64), acc, 0, 0, 0);
            u16* op = qkv + ((long)wi * 256 + rt * 16 + kg * 4) * 224 + nt * 16 + l15;
            #pragma unroll
            for (int rr = 0; rr < 4; ++rr) op[rr * 224] = F2US(acc[rr]);
        }
    }
}

// ---------- K2: MFMA flash attention ----------
// grid 722*2 (window x head-pair), block 128 (2 waves, wave = one head)
#define PSTR 264
__global__ __launch_bounds__(128) void k_attn_mfma(const u16* __restrict__ qkv, u16* __restrict__ attn)
{
    __shared__ __align__(16) u16 vt[2][24 * PSTR];
    __shared__ __align__(16) u16 pls[2][16 * PSTR];

    int wi = blockIdx.x >> 1;
    int pairid = blockIdx.x & 1;
    int wvv = threadIdx.x >> 6;
    int hd = pairid * 2 + wvv;
    int lane = threadIdx.x & 63;
    int l15 = lane & 15;
    int kg = lane >> 4;

    const u16* base = qkv + (long)wi * 256 * 224;
    u16* vtp = vt[wvv];
    u16* plp = pls[wvv];

    const bf16x8 zf = {0,0,0,0,0,0,0,0};
    const f32x4 zc = {0.f,0.f,0.f,0.f};

    for (int rd = 0; rd < 4; ++rd) {
        int tok = rd * 64 + lane;
        const u16* vp = base + tok * 224 + 128 + hd * 24;
        bf16x8 v0 = *(const bf16x8*)(vp);
        bf16x8 v1 = *(const bf16x8*)(vp + 8);
        bf16x8 v2 = *(const bf16x8*)(vp + 16);
        #pragma unroll
        for (int j = 0; j < 8; ++j) {
            vtp[(j)      * PSTR + tok] = (u16)v0[j];
            vtp[(j + 8)  * PSTR + tok] = (u16)v1[j];
            vtp[(j + 16) * PSTR + tok] = (u16)v2[j];
        }
    }

    bf16x8 kfr[16];
    #pragma unroll
    for (int nt = 0; nt < 16; ++nt) {
        int key = nt * 16 + l15;
        kfr[nt] = (kg < 2) ? *(const bf16x8*)(base + key * 224 + 64 + hd * 16 + kg * 8) : zf;
    }
    __syncthreads();

    for (int qt = 0; qt < 16; ++qt) {
        int qtok = qt * 16 + l15;
        bf16x8 qfr = (kg < 2) ? *(const bf16x8*)(base + qtok * 224 + hd * 16 + kg * 8) : zf;

        f32x4 S[16];
        #pragma unroll
        for (int nt = 0; nt < 16; ++nt)
            S[nt] = __builtin_amdgcn_mfma_f32_16x16x32_bf16(qfr, kfr[nt], zc, 0, 0, 0);

        #pragma unroll
        for (int nt = 0; nt < 16; ++nt) S[nt] *= 0.25f;

        float mx[4];
        #pragma unroll
        for (int r = 0; r < 4; ++r) {
            float m = S[0][r];
            #pragma unroll
            for (int nt = 1; nt < 16; ++nt) m = fmaxf(m, S[nt][r]);
            #pragma unroll
            for (int msk = 1; msk < 16; msk <<= 1) m = fmaxf(m, __shfl_xor(m, msk));
            mx[r] = m;
        }
        #pragma unroll
        for (int nt = 0; nt < 16; ++nt) {
            #pragma unroll
            for (int r = 0; r < 4; ++r) S[nt][r] = __expf(S[nt][r] - mx[r]);
        }
        float li[4];
        #pragma unroll
        for (int r = 0; r < 4; ++r) {
            float s = S[0][r];
            #pragma unroll
            for (int nt = 1; nt < 16; ++nt) s += S[nt][r];
            #pragma unroll
            for (int msk = 1; msk < 16; msk <<= 1) s += __shfl_xor(s, msk);
            li[r] = 1.f / s;
        }
        #pragma unroll
        for (int nt = 0; nt < 16; ++nt) {
            #pragma unroll
            for (int r = 0; r < 4; ++r) {
                int R = kg * 4 + r;
                plp[R * PSTR + nt * 16 + l15] = F2US(S[nt][r]);
            }
        }
        __syncthreads();

        f32x4 O0 = zc, O1 = zc;
        int vd1 = 16 + l15;
        #pragma unroll
        for (int ks = 0; ks < 8; ++ks) {
            bf16x8 af = *(const bf16x8*)(plp + l15 * PSTR + ks * 32 + kg * 8);
            bf16x8 b0 = *(const bf16x8*)(vtp + l15 * PSTR + ks * 32 + kg * 8);
            bf16x8 b1 = (l15 < 8) ? *(const bf16x8*)(vtp + vd1 * PSTR + ks * 32 + kg * 8) : zf;
            O0 = __builtin_amdgcn_mfma_f32_16x16x32_bf16(af, b0, O0, 0, 0, 0);
            O1 = __builtin_amdgcn_mfma_f32_16x16x32_bf16(af, b1, O1, 0, 0, 0);
        }
        #pragma unroll
        for (int r = 0; r < 4; ++r) {
            int R = kg * 4 + r;
            long tok = (long)wi * 256 + qt * 16 + R;
            attn[tok * 96 + hd * 24 + l15] = F2US(O0[r] * li[r]);
            if (l15 < 8) attn[tok * 96 + hd * 24 + 16 + l15] = F2US(O1[r] * li[r]);
        }
        __syncthreads();
    }
}

// ---------- K3: proj GEMM -> dense per-window wout[wi][c][token] (no atomics) ----------
// grid 722, block 256 (4 waves); M=256, N=96, K=96
#define WOSTR 264   // LDS row stride (u16): 528B rows, 16B-aligned
__global__ __launch_bounds__(256) void k_proj_mfma(
    const u16* __restrict__ attn, const u16* __restrict__ wprojT,
    u16* __restrict__ wout)
{
    __shared__ __align__(16) u16 cs[96 * WOSTR];
    int wi = blockIdx.x;
    int t = threadIdx.x;
    int wvid = t >> 6, lane = t & 63, l15 = lane & 15, kg = lane >> 4;
    const f32x4 zc = {0.f, 0.f, 0.f, 0.f};

    for (int i = 0; i < 4; ++i) {
        int rt = wvid * 4 + i;
        const u16* ap = attn + ((long)wi * 256 + rt * 16 + l15) * 96 + kg * 8;
        bf16x8 a0 = *(const bf16x8*)(ap);
        bf16x8 a1 = *(const bf16x8*)(ap + 32);
        bf16x8 a2 = *(const bf16x8*)(ap + 64);
        for (int nt = 0; nt < 6; ++nt) {
            const u16* wp = wprojT + (nt * 16 + l15) * 96 + kg * 8;
            f32x4 acc = __builtin_amdgcn_mfma_f32_16x16x32_bf16(a0, *(const bf16x8*)(wp), zc, 0, 0, 0);
            acc = __builtin_amdgcn_mfma_f32_16x16x32_bf16(a1, *(const bf16x8*)(wp + 32), acc, 0, 0, 0);
            acc = __builtin_amdgcn_mfma_f32_16x16x32_bf16(a2, *(const bf16x8*)(wp + 64), acc, 0, 0, 0);
            int c = nt * 16 + l15;
            #pragma unroll
            for (int rr = 0; rr < 4; ++rr) {
                int tok = rt * 16 + kg * 4 + rr;
                cs[c * WOSTR + tok] = F2US(acc[rr]);
            }
        }
    }
    __syncthreads();
    // coalesced write-out: 96 rows x 256 tokens, 16B segments
    u16* wo = wout + (long)wi * 24576;
    for (int seg = t; seg < 3072; seg += 256) {
        int c = seg >> 5, t8 = (seg & 31) << 3;
        *(bf16x8*)(wo + c * 256 + t8) = *(const bf16x8*)(cs + c * WOSTR + t8);
    }
}

// ---------- K4: gather overlapping windows -> x2 (factor pre-applied) ----------
// grid b*96*256 (one block per (b,c,y) row), block 256 (thread = x)
__global__ __launch_bounds__(256) void k_gather(
    const u16* __restrict__ wout, const float* __restrict__ x, float* __restrict__ accb)
{
    int blk = blockIdx.x;
    int y = blk & 255;
    int c = (blk >> 8) % 96;
    int b = blk / (96 * 256);
    int xx = threadIdx.x;

    // y-covering windows (block-uniform)
    int iyl[2]; int ny = 0;
    {
        int c1 = min(17, y / 14), c0 = c1 - 1;
        if (c0 >= 0 && y >= 14 * c0 && y < 14 * c0 + 16) iyl[ny++] = c0;
        if (y >= 14 * c1 && y < 14 * c1 + 16) iyl[ny++] = c1;
        if (y >= 240) iyl[ny++] = 18;
    }
    // x-covering windows (per-thread)
    int ixl[2]; int nx = 0;
    {
        int c1 = min(17, xx / 14), c0 = c1 - 1;
        if (c0 >= 0 && xx >= 14 * c0 && xx < 14 * c0 + 16) ixl[nx++] = c0;
        if (xx >= 14 * c1 && xx < 14 * c1 + 16) ixl[nx++] = c1;
        if (xx >= 240) ixl[nx++] = 18;
    }

    long p = (long)(b * 96 + c) * 65536 + y * 256 + xx;
    float v = (float)(ny * nx) * x[p];
    for (int a = 0; a < ny; ++a) {
        int ty = win_pos(iyl[a]);
        int rowoff = (y - ty) * 16;
        for (int e = 0; e < nx; ++e) {
            int tx = win_pos(ixl[e]);
            int wi = b * 361 + iyl[a] * 19 + ixl[e];
            v += US2F(wout[(long)wi * 24576 + c * 256 + rowoff + (xx - tx)]);
        }
    }
    float f = ((ny == 2) ? 0.5f : 1.f) * ((nx == 2) ? 0.5f : 1.f);
    accb[p] = v * f;
}

// ---------- K5: LN2 + fc1 + GELU (MFMA) ----------
// grid 2048 (64 px/block), block 256 (4 waves); M=64, N=192, K=96
#define XASTR 104
__global__ __launch_bounds__(256) void k_ln2_fc1_mfma(
    const float* __restrict__ accb,
    const float* __restrict__ n2w, const float* __restrict__ n2b,
    const u16* __restrict__ fc1T, const float* __restrict__ fc1b,
    u16* __restrict__ y1)
{
    __shared__ float xs[64 * 97];
    __shared__ __align__(16) u16 xa[64 * XASTR];
    __shared__ float mu_s[64], rs_s[64];
    int p0 = blockIdx.x * 64;
    int b = p0 >> 16, pp = p0 & 65535;
    int tid = threadIdx.x;

    for (int idx = tid; idx < 64 * 96; idx += 256) {
        int c = idx >> 6, px = idx & 63;
        xs[px * 97 + c] = accb[(long)(b * 96 + c) * 65536 + pp + px];
    }
    __syncthreads();
    if (tid < 64) {
        float s = 0.f, ss = 0.f;
        for (int c = 0; c < 96; ++c) { float v = xs[tid * 97 + c]; s += v; ss += v * v; }
        float mu = s * (1.f / 96.f);
        float var = ss * (1.f / 96.f) - mu * mu;
        mu_s[tid] = mu; rs_s[tid] = rsqrtf(var + 1e-5f);
    }
    __syncthreads();
    for (int idx = tid; idx < 64 * 96; idx += 256) {
        int c = idx >> 6, px = idx & 63;
        xa[px * XASTR + c] = F2US((xs[px * 97 + c] - mu_s[px]) * rs_s[px] * n2w[c] + n2b[c]);
    }
    __syncthreads();

    int wvid = tid >> 6, lane = tid & 63, l15 = lane & 15, kg = lane >> 4;
    const f32x4 zc = {0.f, 0.f, 0.f, 0.f};
    bf16x8 a0 = *(const bf16x8*)(xa + (wvid * 16 + l15) * XASTR + 0  + kg * 8);
    bf16x8 a1 = *(const bf16x8*)(xa + (wvid * 16 + l15) * XASTR + 32 + kg * 8);
    bf16x8 a2 = *(const bf16x8*)(xa + (wvid * 16 + l15) * XASTR + 64 + kg * 8);

    for (int nt = 0; nt < 12; ++nt) {
        const u16* wp = fc1T + (nt * 16 + l15) * 96 + kg * 8;
        f32x4 acc = __builtin_amdgcn_mfma_f32_16x16x32_bf16(a0, *(const bf16x8*)(wp), zc, 0, 0, 0);
        acc = __builtin_amdgcn_mfma_f32_16x16x32_bf16(a1, *(const bf16x8*)(wp + 32), acc, 0, 0, 0);
        acc = __builtin_amdgcn_mfma_f32_16x16x32_bf16(a2, *(const bf16x8*)(wp + 64), acc, 0, 0, 0);
        int m = nt * 16 + l15;
        float bb = fc1b[m];
        ushort4 pk;
        pk.x = F2US(gelu_exact(acc[0] + bb));
        pk.y = F2US(gelu_exact(acc[1] + bb));
        pk.z = F2US(gelu_exact(acc[2] + bb));
        pk.w = F2US(gelu_exact(acc[3] + bb));
        *(ushort4*)(y1 + (long)(b * 192 + m) * 65536 + pp + wvid * 16 + kg * 4) = pk;
    }
}

// ---------- K6: depthwise 5x5 conv + GELU + add -> y2 ----------
// grid b*192*4*16 = 24576 (one block per channel-plane 64x16 tile), block 256
// LDS 20x68 fp32 halo tile; one barrier per block; conflict-free (stride 68, lanes consecutive)
__global__ __launch_bounds__(256) void k_dwconv(
    const u16* __restrict__ y1, const float* __restrict__ dww, const float* __restrict__ dwb,
    u16* __restrict__ y2)
{
    __shared__ float tile[20 * 68];
    int blk = blockIdx.x;
    int txt = blk & 3;            // x-tile 0..3
    int tyt = (blk >> 2) & 15;    // y-tile 0..15
    int m   = (blk >> 6) % 192;
    int b   = blk / (64 * 192);
    int bx = txt * 64, by = tyt * 16;
    int tid = threadIdx.x;

    const u16* plane = y1 + (long)(b * 192 + m) * 65536;
    for (int idx = tid; idx < 20 * 68; idx += 256) {
        int ly = idx / 68, lx = idx - ly * 68;
        int sy = by + ly - 2, sx = bx + lx - 2;
        float v = 0.f;
        if (sy >= 0 && sy < 256 && sx >= 0 && sx < 256) v = US2F(plane[sy * 256 + sx]);
        tile[idx] = v;
    }
    // block-uniform weights -> scalar regs
    float w[25];
    #pragma unroll
    for (int j = 0; j < 25; ++j) w[j] = dww[m * 25 + j];
    float bias = dwb[m];
    __syncthreads();

    int tx = tid & 63, ty0 = tid >> 6;
    u16* oplane = y2 + (long)(b * 192 + m) * 65536;
    #pragma unroll
    for (int i = 0; i < 4; ++i) {
        int ty = ty0 * 4 + i;
        float acc = 0.f;
        #pragma unroll
        for (int ky = 0; ky < 5; ++ky)
            #pragma unroll
            for (int kx = 0; kx < 5; ++kx)
                acc += tile[(ty + ky) * 68 + tx + kx] * w[ky * 5 + kx];
        float center = tile[(ty + 2) * 68 + tx + 2];
        float v = center + gelu_exact(acc + bias);
        oplane[(by + ty) * 256 + bx + tx] = F2US(v);
    }
}

// ---------- K7: fc2 + bias + residual (MFMA) ----------
// grid 2048 (64 px/block), block 256 (4 waves); M=64, N=96, K=192
#define Y2STR 200
__global__ __launch_bounds__(256) void k_fc2_mfma(
    const u16* __restrict__ y2, const u16* __restrict__ fc2T, const float* __restrict__ fc2b,
    const float* __restrict__ accb, float* __restrict__ out)
{
    __shared__ __align__(16) u16 ys2[64 * Y2STR];
    int p0 = blockIdx.x * 64;
    int b = p0 >> 16, pp = p0 & 65535;
    int tid = threadIdx.x;
    for (int idx = tid; idx < 64 * 192; idx += 256) {
        int m = idx >> 6, px = idx & 63;
        ys2[px * Y2STR + m] = y2[(long)(b * 192 + m) * 65536 + pp + px];
    }
    __syncthreads();

    int wvid = tid >> 6, lane = tid & 63, l15 = lane & 15, kg = lane >> 4;
    const f32x4 zc = {0.f, 0.f, 0.f, 0.f};
    bf16x8 af[6];
    #pragma unroll
    for (int ks = 0; ks < 6; ++ks)
        af[ks] = *(const bf16x8*)(ys2 + (wvid * 16 + l15) * Y2STR + ks * 32 + kg * 8);

    int pxb = pp + wvid * 16 + kg * 4;

    for (int nt = 0; nt < 6; ++nt) {
        const u16* wp = fc2T + (nt * 16 + l15) * 192 + kg * 8;
        f32x4 acc = zc;
        #pragma unroll
        for (int ks = 0; ks < 6; ++ks)
            acc = __builtin_amdgcn_mfma_f32_16x16x32_bf16(af[ks], *(const bf16x8*)(wp + ks * 32), acc, 0, 0, 0);
        int c = nt * 16 + l15;
        long gbase = (long)(b * 96 + c) * 65536 + pxb;
        float4 av = *(const float4*)(accb + gbase);
        float4 res;
        float bb = fc2b[c];
        res.x = acc[0] + bb + av.x;
        res.y = acc[1] + bb + av.y;
        res.z = acc[2] + bb + av.z;
        res.w = acc[3] + bb + av.w;
        *(float4*)(out + gbase) = res;
    }
}

extern "C" void kernel_launch(void* const* d_in, const int* in_sizes, int n_in,
                              void* d_out, int out_size, void* d_ws, size_t ws_size,
                              hipStream_t stream)
{
    const float* x     = (const float*)d_in[0];
    const float* n1w   = (const float*)d_in[1];
    const float* n1b   = (const float*)d_in[2];
    const float* wq    = (const float*)d_in[3];
    const float* wk    = (const float*)d_in[4];
    const float* wv    = (const float*)d_in[5];
    const float* wproj = (const float*)d_in[6];
    const float* n2w   = (const float*)d_in[7];
    const float* n2b   = (const float*)d_in[8];
    const float* fc1w  = (const float*)d_in[9];
    const float* fc1b  = (const float*)d_in[10];
    const float* dww   = (const float*)d_in[11];
    const float* dwb   = (const float*)d_in[12];
    const float* fc2w  = (const float*)d_in[13];
    const float* fc2b  = (const float*)d_in[14];

    char* ws = (char*)d_ws;
    // memory map (peak 168,759,296 B):
    //   accb fp32 [0, 50.3M)          k_gather -> ln2_fc1, fc2
    //   qkv  bf16 [50.3M, 133.1M)     k_ln_qkv -> k_attn        (dead after attn)
    //   attn bf16 [133.1M, 168.6M)    k_attn -> k_proj          (dead after proj)
    //   wout bf16 [50.3M, 85.8M)      k_proj -> k_gather        (reuses dead qkv head; dead after gather)
    //   y1   bf16 [100.7M, 151.0M)    ln2_fc1 -> dwconv         (dead qkv tail + dead attn head)
    //   y2   bf16 [50.3M, 100.7M)     dwconv -> fc2             (dead wout + dead qkv; below y1)
    //   wT   bf16 [168.6M, +135168)   k_prep -> all GEMMs
    float* accb = (float*)ws;
    u16* qkv  = (u16*)(ws + 50331648);
    u16* attn = (u16*)(ws + 133136384);
    u16* wout = (u16*)(ws + 50331648);
    u16* y1   = (u16*)(ws + 100663296);
    u16* y2   = (u16*)(ws + 50331648);
    u16* wT   = (u16*)(ws + 168624128);
    u16* wqkvT  = wT;
    u16* wprojT = wT + 21504;
    u16* fc1T   = wT + 30720;
    u16* fc2T   = wT + 49152;
    float* out = (float*)d_out;

    k_prep<<<264, 256, 0, stream>>>(wq, wk, wv, wproj, fc1w, fc2w, wT);
    k_ln_qkv_mfma<<<722, 256, 0, stream>>>(x, n1w, n1b, wqkvT, qkv);
    k_attn_mfma<<<1444, 128, 0, stream>>>(qkv, attn);
    k_proj_mfma<<<722, 256, 0, stream>>>(attn, wprojT, wout);
    k_gather<<<49152, 256, 0, stream>>>(wout, x, accb);
    k_ln2_fc1_mfma<<<2048, 256, 0, stream>>>(accb, n2w, n2b, fc1T, fc1b, y1);
    k_dwconv<<<24576, 256, 0, stream>>>(y1, dww, dwb, y2);
    k_fc2_mfma<<<2048, 256, 0, stream>>>(y2, fc2T, fc2b, accb, out);
}